// Round 2
// baseline (1062.850 us; speedup 1.0000x reference)
//
#include <hip/hip_runtime.h>

#define N_NODES 20000
#define N_EDGES 200000
// H = 128, 3H = 384, RBF = 64, HEADS = 8, HD = 16

__device__ __forceinline__ float silu_f(float x) { return x / (1.f + __expf(-x)); }

// ---- register-tiled helper: 8 rows (row0..row0+7) x 1 col, K = KDIM ----
template <int KDIM>
__device__ __forceinline__ void gemm8(const float* __restrict__ w, int wstride,
                                      const float* src, int srcstride, int row0,
                                      float acc[8]) {
  for (int k = 0; k < KDIM; k += 4) {
    float w0 = w[(k + 0) * wstride];
    float w1 = w[(k + 1) * wstride];
    float w2 = w[(k + 2) * wstride];
    float w3 = w[(k + 3) * wstride];
#pragma unroll
    for (int n = 0; n < 8; n++) {
      const float4 a = *(const float4*)(src + (row0 + n) * srcstride + k);
      acc[n] = fmaf(a.x, w0, acc[n]);
      acc[n] = fmaf(a.y, w1, acc[n]);
      acc[n] = fmaf(a.z, w2, acc[n]);
      acc[n] = fmaf(a.w, w3, acc[n]);
    }
  }
}

// same but three output columns sharing the A-operand (for vec_w / o_w)
template <int KDIM>
__device__ __forceinline__ void gemm8x3(const float* __restrict__ wA,
                                        const float* __restrict__ wB,
                                        const float* __restrict__ wC, int wstride,
                                        const float* src, int srcstride, int row0,
                                        float a1[8], float a2[8], float a3[8]) {
  for (int k = 0; k < KDIM; k += 4) {
    float uA0 = wA[(k + 0) * wstride], uA1 = wA[(k + 1) * wstride];
    float uA2 = wA[(k + 2) * wstride], uA3 = wA[(k + 3) * wstride];
    float uB0 = wB[(k + 0) * wstride], uB1 = wB[(k + 1) * wstride];
    float uB2 = wB[(k + 2) * wstride], uB3 = wB[(k + 3) * wstride];
    float uC0 = wC[(k + 0) * wstride], uC1 = wC[(k + 1) * wstride];
    float uC2 = wC[(k + 2) * wstride], uC3 = wC[(k + 3) * wstride];
#pragma unroll
    for (int n = 0; n < 8; n++) {
      const float4 a = *(const float4*)(src + (row0 + n) * srcstride + k);
      a1[n] = fmaf(a.x, uA0, a1[n]); a1[n] = fmaf(a.y, uA1, a1[n]);
      a1[n] = fmaf(a.z, uA2, a1[n]); a1[n] = fmaf(a.w, uA3, a1[n]);
      a2[n] = fmaf(a.x, uB0, a2[n]); a2[n] = fmaf(a.y, uB1, a2[n]);
      a2[n] = fmaf(a.z, uB2, a2[n]); a2[n] = fmaf(a.w, uB3, a2[n]);
      a3[n] = fmaf(a.x, uC0, a3[n]); a3[n] = fmaf(a.y, uC1, a3[n]);
      a3[n] = fmaf(a.z, uC2, a3[n]); a3[n] = fmaf(a.w, uC3, a3[n]);
    }
  }
}

// ================= Phase A: node MLP + LN + QKV + vec einsum =================
__global__ __launch_bounds__(256, 2) void node_kernel(
    const float* __restrict__ x, const float* __restrict__ vec,
    const float* __restrict__ na, const float* __restrict__ w1,
    const float* __restrict__ b1, const float* __restrict__ w2,
    const float* __restrict__ b2, const float* __restrict__ lng,
    const float* __restrict__ lnb, const float* __restrict__ qw,
    const float* __restrict__ qb, const float* __restrict__ kw,
    const float* __restrict__ kb, const float* __restrict__ vw,
    const float* __restrict__ vb, const float* __restrict__ vecw,
    float* __restrict__ q_o, float* __restrict__ k_o, float* __restrict__ v_o,
    float* __restrict__ vdot_o, float* __restrict__ vec3_o) {
  __shared__ float in_s[16][256];
  __shared__ float vec_s[16][384];
  __shared__ float h1_s[16][128];
  __shared__ float h_s[16][128];

  const int t = threadIdx.x;
  const int ch = t & 127, g = t >> 7;
  const int node0 = blockIdx.x * 16;

  for (int idx = t; idx < 16 * 256; idx += 256) {
    int n = idx >> 8, c = idx & 255;
    in_s[n][c] = (c < 128) ? x[(node0 + n) * 128 + c]
                           : na[(node0 + n) * 128 + (c - 128)];
  }
  for (int idx = t; idx < 16 * 384; idx += 256) {
    int n = idx / 384, r = idx - n * 384;
    vec_s[n][r] = vec[(node0 + n) * 384 + r];
  }
  __syncthreads();

  // ---- mix GEMM1: [16,256] @ [256,128] -> silu -> h1_s ----
  {
    float acc[8] = {0, 0, 0, 0, 0, 0, 0, 0};
    gemm8<256>(w1 + ch, 128, &in_s[0][0], 256, g * 8, acc);
    float bb = b1[ch];
#pragma unroll
    for (int n = 0; n < 8; n++) h1_s[g * 8 + n][ch] = silu_f(acc[n] + bb);
  }
  __syncthreads();

  // ---- mix GEMM2: [16,128] @ [128,128] -> h_s (pre-LN) ----
  {
    float acc[8] = {0, 0, 0, 0, 0, 0, 0, 0};
    gemm8<128>(w2 + ch, 128, &h1_s[0][0], 128, g * 8, acc);
    float bb = b2[ch];
#pragma unroll
    for (int n = 0; n < 8; n++) h_s[g * 8 + n][ch] = acc[n] + bb;
  }
  __syncthreads();

  // ---- LayerNorm: wave w handles nodes w*4..w*4+3 ----
  {
    int wave = t >> 6, lane = t & 63;
    for (int nn = wave * 4; nn < wave * 4 + 4; nn++) {
      float v0 = h_s[nn][lane], v1 = h_s[nn][64 + lane];
      float s = v0 + v1, ss = v0 * v0 + v1 * v1;
#pragma unroll
      for (int m = 1; m < 64; m <<= 1) {
        s += __shfl_xor(s, m);
        ss += __shfl_xor(ss, m);
      }
      float mean = s * (1.f / 128.f);
      float var = ss * (1.f / 128.f) - mean * mean;
      float rs = rsqrtf(var + 1e-5f);
      h_s[nn][lane] = (v0 - mean) * rs * lng[lane] + lnb[lane];
      h_s[nn][64 + lane] = (v1 - mean) * rs * lng[64 + lane] + lnb[64 + lane];
    }
  }
  __syncthreads();

  // ---- q, k, v projections ----
#pragma unroll
  for (int cb = 0; cb < 5; cb++) {
    const float* wsel;
    const float* bsel;
    float* osel;
    int wstr, ostr;
    if (cb == 0) { wsel = qw + ch; bsel = qb + ch; osel = q_o + ch; wstr = 128; ostr = 128; }
    else if (cb == 1) { wsel = kw + ch; bsel = kb + ch; osel = k_o + ch; wstr = 128; ostr = 128; }
    else { int cc = (cb - 2) * 128 + ch; wsel = vw + cc; bsel = vb + cc; osel = v_o + cc; wstr = 384; ostr = 384; }
    float acc[8] = {0, 0, 0, 0, 0, 0, 0, 0};
    gemm8<128>(wsel, wstr, &h_s[0][0], 128, g * 8, acc);
    float bb = *bsel;
#pragma unroll
    for (int n = 0; n < 8; n++) osel[(size_t)(node0 + g * 8 + n) * ostr] = acc[n] + bb;
  }

  // ---- vec einsum: vp = vec @ vec_w ; vec_dot = sum_c vp1*vp2 ; store vp3 ----
  {
    float vdot[8] = {0, 0, 0, 0, 0, 0, 0, 0};
#pragma unroll
    for (int c = 0; c < 3; c++) {
      float a1[8] = {0, 0, 0, 0, 0, 0, 0, 0};
      float a2[8] = {0, 0, 0, 0, 0, 0, 0, 0};
      float a3[8] = {0, 0, 0, 0, 0, 0, 0, 0};
      gemm8x3<128>(vecw + ch, vecw + 128 + ch, vecw + 256 + ch, 384,
                   &vec_s[0][c * 128], 384, g * 8, a1, a2, a3);
#pragma unroll
      for (int n = 0; n < 8; n++) {
        vdot[n] += a1[n] * a2[n];
        vec3_o[(size_t)(node0 + g * 8 + n) * 384 + c * 128 + ch] = a3[n];
      }
    }
#pragma unroll
    for (int n = 0; n < 8; n++)
      vdot_o[(size_t)(node0 + g * 8 + n) * 128 + ch] = vdot[n];
  }
}

// ================= Phase B: per-edge dk/dv GEMM + attention + scatter ========
__global__ __launch_bounds__(256, 2) void edge_kernel(
    const int* __restrict__ ei, const float* __restrict__ r_ij,
    const float* __restrict__ f_ij, const float* __restrict__ d_ij,
    const float* __restrict__ dkw, const float* __restrict__ dkb,
    const float* __restrict__ dvw, const float* __restrict__ dvb,
    const float* __restrict__ q_ws, const float* __restrict__ k_ws,
    const float* __restrict__ v_ws, const float* __restrict__ vec_in,
    float* __restrict__ x_agg, float* __restrict__ vec_agg) {
  __shared__ float f_s[32][68];
  __shared__ float dkv_s[32][512];
  __shared__ int j_s[32];
  __shared__ int i_s[32];
  __shared__ float cut_s[32];
  __shared__ float d_s[32][3];

  const int t = threadIdx.x;
  const int n_tiles = N_EDGES / 32;

  for (int tile = blockIdx.x; tile < n_tiles; tile += gridDim.x) {
    const int e0 = tile * 32;
    // ---- stage f tile (coalesced) + edge metadata ----
    {
      int e = t >> 3, kk = (t & 7) * 8;
      const float4* src = (const float4*)&f_ij[(size_t)(e0 + e) * 64 + kk];
      float4 f0 = src[0], f1 = src[1];
      *(float4*)&f_s[e][kk] = f0;
      *(float4*)&f_s[e][kk + 4] = f1;
    }
    if (t < 32) {
      j_s[t] = ei[e0 + t];
      i_s[t] = ei[N_EDGES + e0 + t];
      float r = r_ij[e0 + t];
      cut_s[t] = 0.5f * (__cosf(r * 0.31415926535f) + 1.f) * (r < 10.f ? 1.f : 0.f);
    }
    if (t >= 32 && t < 128) {
      int idx = t - 32;
      int e = idx & 31, c = idx >> 5;
      d_s[e][c] = d_ij[(e0 + e) * 3 + c];
    }
    __syncthreads();

    // ---- dkv GEMM: [32 edges,64] @ [64,512] -> dkv_s (bias+silu fused) ----
    {
      const int cg = t & 63, eg = t >> 6;
      const int cc0 = cg * 8, eb = eg * 8;
      float acc[8][8];
#pragma unroll
      for (int e = 0; e < 8; e++)
#pragma unroll
        for (int c = 0; c < 8; c++) acc[e][c] = 0.f;

      const float* wbase;
      int wstride;
      const float* bp;
      if (cc0 < 128) { wbase = dkw + cc0; wstride = 128; bp = dkb + cc0; }
      else { wbase = dvw + (cc0 - 128); wstride = 384; bp = dvb + (cc0 - 128); }

      for (int k = 0; k < 64; k += 2) {
        float4 wa0 = *(const float4*)(wbase + k * wstride);
        float4 wa1 = *(const float4*)(wbase + k * wstride + 4);
        float4 wb0 = *(const float4*)(wbase + (k + 1) * wstride);
        float4 wb1 = *(const float4*)(wbase + (k + 1) * wstride + 4);
#pragma unroll
        for (int e = 0; e < 8; e++) {
          float2 fv = *(const float2*)&f_s[eb + e][k];
          acc[e][0] = fmaf(fv.x, wa0.x, acc[e][0]);
          acc[e][1] = fmaf(fv.x, wa0.y, acc[e][1]);
          acc[e][2] = fmaf(fv.x, wa0.z, acc[e][2]);
          acc[e][3] = fmaf(fv.x, wa0.w, acc[e][3]);
          acc[e][4] = fmaf(fv.x, wa1.x, acc[e][4]);
          acc[e][5] = fmaf(fv.x, wa1.y, acc[e][5]);
          acc[e][6] = fmaf(fv.x, wa1.z, acc[e][6]);
          acc[e][7] = fmaf(fv.x, wa1.w, acc[e][7]);
          acc[e][0] = fmaf(fv.y, wb0.x, acc[e][0]);
          acc[e][1] = fmaf(fv.y, wb0.y, acc[e][1]);
          acc[e][2] = fmaf(fv.y, wb0.z, acc[e][2]);
          acc[e][3] = fmaf(fv.y, wb0.w, acc[e][3]);
          acc[e][4] = fmaf(fv.y, wb1.x, acc[e][4]);
          acc[e][5] = fmaf(fv.y, wb1.y, acc[e][5]);
          acc[e][6] = fmaf(fv.y, wb1.z, acc[e][6]);
          acc[e][7] = fmaf(fv.y, wb1.w, acc[e][7]);
        }
      }
      float bsv[8];
#pragma unroll
      for (int i = 0; i < 8; i++) bsv[i] = bp[i];
#pragma unroll
      for (int e = 0; e < 8; e++) {
#pragma unroll
        for (int i = 0; i < 8; i++)
          dkv_s[eb + e][cc0 + i] = silu_f(acc[e][i] + bsv[i]);
      }
    }
    __syncthreads();

    // ---- attention + messages + scatter ----
    {
      const int ch = t & 127, g2 = t >> 7;
      const int h = ch >> 4, d = ch & 15;
      const int vcol = h * 48 + d;  // v/dv reshape(8,48) flat column
      for (int ee = g2; ee < 32; ee += 2) {
        int j = j_s[ee], i = i_s[ee];
        float ddk = dkv_s[ee][ch];
        float qv = q_ws[(size_t)i * 128 + ch];
        float kv = k_ws[(size_t)j * 128 + ch];
        float p = qv * kv * ddk;
        p += __shfl_xor(p, 1);
        p += __shfl_xor(p, 2);
        p += __shfl_xor(p, 4);
        p += __shfl_xor(p, 8);
        float a = silu_f(p) * cut_s[ee];
        float dv0 = dkv_s[ee][128 + vcol];
        float dv1 = dkv_s[ee][128 + vcol + 16];
        float dv2 = dkv_s[ee][128 + vcol + 32];
        float v0 = v_ws[(size_t)j * 384 + vcol];
        float v1 = v_ws[(size_t)j * 384 + vcol + 16];
        float v2 = v_ws[(size_t)j * 384 + vcol + 32];
        float xm = v0 * dv0 * a;
        float v1m = v1 * dv1, v2m = v2 * dv2;
        atomicAdd(&x_agg[(size_t)i * 128 + ch], xm);
#pragma unroll
        for (int c = 0; c < 3; c++) {
          float vm = vec_in[(size_t)j * 384 + c * 128 + ch] * v1m + v2m * d_s[ee][c];
          atomicAdd(&vec_agg[(size_t)i * 384 + c * 128 + ch], vm);
        }
      }
    }
    __syncthreads();
  }
}

// ================= Phase C: output projection + epilogue =====================
__global__ __launch_bounds__(256, 2) void out_kernel(
    const float* __restrict__ x_agg, const float* __restrict__ ow,
    const float* __restrict__ ob, const float* __restrict__ vdot,
    const float* __restrict__ vec3, const float* __restrict__ vec_agg,
    float* __restrict__ dx, float* __restrict__ dvec) {
  __shared__ float xs[16][128];
  const int t = threadIdx.x;
  const int ch = t & 127, g = t >> 7;
  const int node0 = blockIdx.x * 16;

  for (int idx = t; idx < 16 * 128; idx += 256) {
    int n = idx >> 7, c = idx & 127;
    xs[n][c] = x_agg[(size_t)(node0 + n) * 128 + c];
  }
  __syncthreads();

  float a1[8] = {0, 0, 0, 0, 0, 0, 0, 0};
  float a2[8] = {0, 0, 0, 0, 0, 0, 0, 0};
  float a3[8] = {0, 0, 0, 0, 0, 0, 0, 0};
  gemm8x3<128>(ow + ch, ow + 128 + ch, ow + 256 + ch, 384, &xs[0][0], 128,
               g * 8, a1, a2, a3);
  float b1v = ob[ch], b2v = ob[128 + ch], b3v = ob[256 + ch];
#pragma unroll
  for (int n = 0; n < 8; n++) {
    int node = node0 + g * 8 + n;
    float o1 = a1[n] + b1v, o2 = a2[n] + b2v, o3 = a3[n] + b3v;
    dx[(size_t)node * 128 + ch] = vdot[(size_t)node * 128 + ch] * o2 + o3;
#pragma unroll
    for (int c = 0; c < 3; c++) {
      size_t off = (size_t)node * 384 + c * 128 + ch;
      dvec[off] = vec3[off] * o1 + vec_agg[off];
    }
  }
}

extern "C" void kernel_launch(void* const* d_in, const int* in_sizes, int n_in,
                              void* d_out, int out_size, void* d_ws,
                              size_t ws_size, hipStream_t stream) {
  const float* x = (const float*)d_in[0];
  const float* vec = (const float*)d_in[1];
  const float* na = (const float*)d_in[2];
  const int* ei = (const int*)d_in[3];
  const float* r_ij = (const float*)d_in[4];
  const float* f_ij = (const float*)d_in[5];
  const float* d_ijp = (const float*)d_in[6];
  const float* w1 = (const float*)d_in[7];
  const float* b1 = (const float*)d_in[8];
  const float* w2 = (const float*)d_in[9];
  const float* b2 = (const float*)d_in[10];
  const float* lng = (const float*)d_in[11];
  const float* lnb = (const float*)d_in[12];
  const float* qw = (const float*)d_in[13];
  const float* qb = (const float*)d_in[14];
  const float* kw = (const float*)d_in[15];
  const float* kb = (const float*)d_in[16];
  const float* vw = (const float*)d_in[17];
  const float* vb = (const float*)d_in[18];
  const float* ow = (const float*)d_in[19];
  const float* ob = (const float*)d_in[20];
  const float* vecw = (const float*)d_in[21];
  const float* dkw = (const float*)d_in[22];
  const float* dkb = (const float*)d_in[23];
  const float* dvw = (const float*)d_in[24];
  const float* dvb = (const float*)d_in[25];

  float* ws = (float*)d_ws;
  const size_t NH = (size_t)N_NODES * 128;
  const size_t NH3 = (size_t)N_NODES * 384;
  float* q_o = ws;                 // N*H
  float* k_o = q_o + NH;           // N*H
  float* v_o = k_o + NH;           // N*3H
  float* vdot_o = v_o + NH3;       // N*H
  float* vec3_o = vdot_o + NH;     // N*3H
  float* x_agg = vec3_o + NH3;     // N*H
  float* vec_agg = x_agg + NH;     // N*3H

  hipMemsetAsync(x_agg, 0, (NH + NH3) * sizeof(float), stream);

  node_kernel<<<N_NODES / 16, 256, 0, stream>>>(
      x, vec, na, w1, b1, w2, b2, lng, lnb, qw, qb, kw, kb, vw, vb, vecw, q_o,
      k_o, v_o, vdot_o, vec3_o);

  edge_kernel<<<N_EDGES / 32, 256, 0, stream>>>(
      ei, r_ij, f_ij, d_ijp, dkw, dkb, dvw, dvb, q_o, k_o, v_o, vec, x_agg,
      vec_agg);

  float* dx = (float*)d_out;
  float* dvec = dx + NH;
  out_kernel<<<N_NODES / 16, 256, 0, stream>>>(x_agg, ow, ob, vdot_o, vec3_o,
                                               vec_agg, dx, dvec);
}

// Round 3
// 871.948 us; speedup vs baseline: 1.2189x; 1.2189x over previous
//
#include <hip/hip_runtime.h>

#define N_NODES 20000
#define N_EDGES 200000
#define TILE 16
// H = 128, 3H = 384, RBF = 64, HEADS = 8, HD = 16

__device__ __forceinline__ float silu_f(float x) { return x / (1.f + __expf(-x)); }

// ---- register-tiled helper: 8 rows x 1 col, K = KDIM ----
template <int KDIM>
__device__ __forceinline__ void gemm8(const float* __restrict__ w, int wstride,
                                      const float* src, int srcstride, int row0,
                                      float acc[8]) {
  for (int k = 0; k < KDIM; k += 4) {
    float w0 = w[(k + 0) * wstride];
    float w1 = w[(k + 1) * wstride];
    float w2 = w[(k + 2) * wstride];
    float w3 = w[(k + 3) * wstride];
#pragma unroll
    for (int n = 0; n < 8; n++) {
      const float4 a = *(const float4*)(src + (row0 + n) * srcstride + k);
      acc[n] = fmaf(a.x, w0, acc[n]);
      acc[n] = fmaf(a.y, w1, acc[n]);
      acc[n] = fmaf(a.z, w2, acc[n]);
      acc[n] = fmaf(a.w, w3, acc[n]);
    }
  }
}

template <int KDIM>
__device__ __forceinline__ void gemm8x3(const float* __restrict__ wA,
                                        const float* __restrict__ wB,
                                        const float* __restrict__ wC, int wstride,
                                        const float* src, int srcstride, int row0,
                                        float a1[8], float a2[8], float a3[8]) {
  for (int k = 0; k < KDIM; k += 4) {
    float uA0 = wA[(k + 0) * wstride], uA1 = wA[(k + 1) * wstride];
    float uA2 = wA[(k + 2) * wstride], uA3 = wA[(k + 3) * wstride];
    float uB0 = wB[(k + 0) * wstride], uB1 = wB[(k + 1) * wstride];
    float uB2 = wB[(k + 2) * wstride], uB3 = wB[(k + 3) * wstride];
    float uC0 = wC[(k + 0) * wstride], uC1 = wC[(k + 1) * wstride];
    float uC2 = wC[(k + 2) * wstride], uC3 = wC[(k + 3) * wstride];
#pragma unroll
    for (int n = 0; n < 8; n++) {
      const float4 a = *(const float4*)(src + (row0 + n) * srcstride + k);
      a1[n] = fmaf(a.x, uA0, a1[n]); a1[n] = fmaf(a.y, uA1, a1[n]);
      a1[n] = fmaf(a.z, uA2, a1[n]); a1[n] = fmaf(a.w, uA3, a1[n]);
      a2[n] = fmaf(a.x, uB0, a2[n]); a2[n] = fmaf(a.y, uB1, a2[n]);
      a2[n] = fmaf(a.z, uB2, a2[n]); a2[n] = fmaf(a.w, uB3, a2[n]);
      a3[n] = fmaf(a.x, uC0, a3[n]); a3[n] = fmaf(a.y, uC1, a3[n]);
      a3[n] = fmaf(a.z, uC2, a3[n]); a3[n] = fmaf(a.w, uC3, a3[n]);
    }
  }
}

// ================= CSR build: histogram -> scan -> scatter ==================
__global__ void hist_kernel(const int* __restrict__ ei, int* __restrict__ counts) {
  int e = blockIdx.x * 256 + threadIdx.x;
  if (e < N_EDGES) atomicAdd(&counts[ei[N_EDGES + e]], 1);
}

__global__ __launch_bounds__(1024) void scan_kernel(const int* __restrict__ counts,
                                                    int* __restrict__ offsets) {
  __shared__ int buf[1024];
  __shared__ int carry_s;
  const int t = threadIdx.x;
  if (t == 0) carry_s = 0;
  __syncthreads();
  for (int base = 0; base < N_NODES; base += 1024) {
    int v = (base + t < N_NODES) ? counts[base + t] : 0;
    buf[t] = v;
    __syncthreads();
    for (int off = 1; off < 1024; off <<= 1) {
      int add = (t >= off) ? buf[t - off] : 0;
      __syncthreads();
      buf[t] += add;
      __syncthreads();
    }
    int incl = buf[t];
    int c = carry_s;
    if (base + t < N_NODES) offsets[base + t] = c + incl - v;
    __syncthreads();
    if (t == 1023) carry_s = c + incl;
    __syncthreads();
  }
}

__global__ void scatter_kernel(const int* __restrict__ ei,
                               const int* __restrict__ offsets,
                               int* __restrict__ cursor, int* __restrict__ perm) {
  int e = blockIdx.x * 256 + threadIdx.x;
  if (e < N_EDGES) {
    int i = ei[N_EDGES + e];
    int slot = atomicAdd(&cursor[i], 1);
    perm[offsets[i] + slot] = e;
  }
}

// ================= Phase A: node MLP + LN + QKV + vec einsum =================
__global__ __launch_bounds__(256, 2) void node_kernel(
    const float* __restrict__ x, const float* __restrict__ vec,
    const float* __restrict__ na, const float* __restrict__ w1,
    const float* __restrict__ b1, const float* __restrict__ w2,
    const float* __restrict__ b2, const float* __restrict__ lng,
    const float* __restrict__ lnb, const float* __restrict__ qw,
    const float* __restrict__ qb, const float* __restrict__ kw,
    const float* __restrict__ kb, const float* __restrict__ vw,
    const float* __restrict__ vb, const float* __restrict__ vecw,
    float* __restrict__ q_o, float* __restrict__ k_o, float* __restrict__ v_o,
    float* __restrict__ vdot_o, float* __restrict__ vec3_o) {
  __shared__ float in_s[16][256];
  __shared__ float vec_s[16][384];
  __shared__ float h1_s[16][128];
  __shared__ float h_s[16][128];

  const int t = threadIdx.x;
  const int ch = t & 127, g = t >> 7;
  const int node0 = blockIdx.x * 16;

  for (int idx = t; idx < 16 * 256; idx += 256) {
    int n = idx >> 8, c = idx & 255;
    in_s[n][c] = (c < 128) ? x[(node0 + n) * 128 + c]
                           : na[(node0 + n) * 128 + (c - 128)];
  }
  for (int idx = t; idx < 16 * 384; idx += 256) {
    int n = idx / 384, r = idx - n * 384;
    vec_s[n][r] = vec[(node0 + n) * 384 + r];
  }
  __syncthreads();

  {
    float acc[8] = {0, 0, 0, 0, 0, 0, 0, 0};
    gemm8<256>(w1 + ch, 128, &in_s[0][0], 256, g * 8, acc);
    float bb = b1[ch];
#pragma unroll
    for (int n = 0; n < 8; n++) h1_s[g * 8 + n][ch] = silu_f(acc[n] + bb);
  }
  __syncthreads();

  {
    float acc[8] = {0, 0, 0, 0, 0, 0, 0, 0};
    gemm8<128>(w2 + ch, 128, &h1_s[0][0], 128, g * 8, acc);
    float bb = b2[ch];
#pragma unroll
    for (int n = 0; n < 8; n++) h_s[g * 8 + n][ch] = acc[n] + bb;
  }
  __syncthreads();

  {
    int wave = t >> 6, lane = t & 63;
    for (int nn = wave * 4; nn < wave * 4 + 4; nn++) {
      float v0 = h_s[nn][lane], v1 = h_s[nn][64 + lane];
      float s = v0 + v1, ss = v0 * v0 + v1 * v1;
#pragma unroll
      for (int m = 1; m < 64; m <<= 1) {
        s += __shfl_xor(s, m);
        ss += __shfl_xor(ss, m);
      }
      float mean = s * (1.f / 128.f);
      float var = ss * (1.f / 128.f) - mean * mean;
      float rs = rsqrtf(var + 1e-5f);
      h_s[nn][lane] = (v0 - mean) * rs * lng[lane] + lnb[lane];
      h_s[nn][64 + lane] = (v1 - mean) * rs * lng[64 + lane] + lnb[64 + lane];
    }
  }
  __syncthreads();

#pragma unroll
  for (int cb = 0; cb < 5; cb++) {
    const float* wsel;
    const float* bsel;
    float* osel;
    int wstr, ostr;
    if (cb == 0) { wsel = qw + ch; bsel = qb + ch; osel = q_o + ch; wstr = 128; ostr = 128; }
    else if (cb == 1) { wsel = kw + ch; bsel = kb + ch; osel = k_o + ch; wstr = 128; ostr = 128; }
    else { int cc = (cb - 2) * 128 + ch; wsel = vw + cc; bsel = vb + cc; osel = v_o + cc; wstr = 384; ostr = 384; }
    float acc[8] = {0, 0, 0, 0, 0, 0, 0, 0};
    gemm8<128>(wsel, wstr, &h_s[0][0], 128, g * 8, acc);
    float bb = *bsel;
#pragma unroll
    for (int n = 0; n < 8; n++) osel[(size_t)(node0 + g * 8 + n) * ostr] = acc[n] + bb;
  }

  {
    float vdot[8] = {0, 0, 0, 0, 0, 0, 0, 0};
#pragma unroll
    for (int c = 0; c < 3; c++) {
      float a1[8] = {0, 0, 0, 0, 0, 0, 0, 0};
      float a2[8] = {0, 0, 0, 0, 0, 0, 0, 0};
      float a3[8] = {0, 0, 0, 0, 0, 0, 0, 0};
      gemm8x3<128>(vecw + ch, vecw + 128 + ch, vecw + 256 + ch, 384,
                   &vec_s[0][c * 128], 384, g * 8, a1, a2, a3);
#pragma unroll
      for (int n = 0; n < 8; n++) {
        vdot[n] += a1[n] * a2[n];
        vec3_o[(size_t)(node0 + g * 8 + n) * 384 + c * 128 + ch] = a3[n];
      }
    }
#pragma unroll
    for (int n = 0; n < 8; n++)
      vdot_o[(size_t)(node0 + g * 8 + n) * 128 + ch] = vdot[n];
  }
}

// ====== Phase B: sorted-edge dk/dv GEMM + attention + run-accumulated scatter
__global__ __launch_bounds__(256, 4) void edge_kernel(
    const int* __restrict__ ei, const int* __restrict__ perm,
    const float* __restrict__ r_ij, const float* __restrict__ f_ij,
    const float* __restrict__ d_ij, const float* __restrict__ dkw,
    const float* __restrict__ dkb, const float* __restrict__ dvw,
    const float* __restrict__ dvb, const float* __restrict__ q_ws,
    const float* __restrict__ k_ws, const float* __restrict__ v_ws,
    const float* __restrict__ vec_in, float* __restrict__ x_agg,
    float* __restrict__ vec_agg) {
  __shared__ float f_s[TILE][68];
  __shared__ float dkv_s[TILE][512];
  __shared__ int j_s[TILE];
  __shared__ int i_s[TILE];
  __shared__ float cut_s[TILE];
  __shared__ float d_s[TILE][3];

  const int t = threadIdx.x;
  const int e0 = blockIdx.x * TILE;

  // ---- stage edge metadata (sorted order via perm) ----
  if (t < TILE) {
    int e = perm[e0 + t];
    j_s[t] = ei[e];
    i_s[t] = ei[N_EDGES + e];
    float r = r_ij[e];
    cut_s[t] = 0.5f * (__cosf(r * 0.31415926535f) + 1.f) * (r < 10.f ? 1.f : 0.f);
    d_s[t][0] = d_ij[e * 3 + 0];
    d_s[t][1] = d_ij[e * 3 + 1];
    d_s[t][2] = d_ij[e * 3 + 2];
  }
  // ---- stage f tile: 16 rows x 64, 16 threads/row x float4 ----
  {
    int row = t >> 4, col = (t & 15) * 4;
    int e = perm[e0 + row];
    *(float4*)&f_s[row][col] = *(const float4*)&f_ij[(size_t)e * 64 + col];
  }
  __syncthreads();

  // ---- dkv GEMM: [16,64] @ [64,512] -> dkv_s (bias+silu fused) ----
  {
    const int cg = t & 63, eg = t >> 6;
    const int cc0 = cg * 8, eb = eg * 4;
    float acc[4][8];
#pragma unroll
    for (int e = 0; e < 4; e++)
#pragma unroll
      for (int c = 0; c < 8; c++) acc[e][c] = 0.f;

    const float* wbase;
    int wstride;
    const float* bp;
    if (cc0 < 128) { wbase = dkw + cc0; wstride = 128; bp = dkb + cc0; }
    else { wbase = dvw + (cc0 - 128); wstride = 384; bp = dvb + (cc0 - 128); }

    for (int k = 0; k < 64; k += 2) {
      float4 wa0 = *(const float4*)(wbase + k * wstride);
      float4 wa1 = *(const float4*)(wbase + k * wstride + 4);
      float4 wb0 = *(const float4*)(wbase + (k + 1) * wstride);
      float4 wb1 = *(const float4*)(wbase + (k + 1) * wstride + 4);
#pragma unroll
      for (int e = 0; e < 4; e++) {
        float2 fv = *(const float2*)&f_s[eb + e][k];
        acc[e][0] = fmaf(fv.x, wa0.x, acc[e][0]);
        acc[e][1] = fmaf(fv.x, wa0.y, acc[e][1]);
        acc[e][2] = fmaf(fv.x, wa0.z, acc[e][2]);
        acc[e][3] = fmaf(fv.x, wa0.w, acc[e][3]);
        acc[e][4] = fmaf(fv.x, wa1.x, acc[e][4]);
        acc[e][5] = fmaf(fv.x, wa1.y, acc[e][5]);
        acc[e][6] = fmaf(fv.x, wa1.z, acc[e][6]);
        acc[e][7] = fmaf(fv.x, wa1.w, acc[e][7]);
        acc[e][0] = fmaf(fv.y, wb0.x, acc[e][0]);
        acc[e][1] = fmaf(fv.y, wb0.y, acc[e][1]);
        acc[e][2] = fmaf(fv.y, wb0.z, acc[e][2]);
        acc[e][3] = fmaf(fv.y, wb0.w, acc[e][3]);
        acc[e][4] = fmaf(fv.y, wb1.x, acc[e][4]);
        acc[e][5] = fmaf(fv.y, wb1.y, acc[e][5]);
        acc[e][6] = fmaf(fv.y, wb1.z, acc[e][6]);
        acc[e][7] = fmaf(fv.y, wb1.w, acc[e][7]);
      }
    }
    float bsv[8];
#pragma unroll
    for (int i = 0; i < 8; i++) bsv[i] = bp[i];
#pragma unroll
    for (int e = 0; e < 4; e++) {
#pragma unroll
      for (int i = 0; i < 8; i++)
        dkv_s[eb + e][cc0 + i] = silu_f(acc[e][i] + bsv[i]);
    }
  }
  __syncthreads();

  // ---- attention + messages + run-accumulated scatter ----
  {
    const int ch = t & 127, g2 = t >> 7;
    const int h = ch >> 4, d = ch & 15;
    const int vcol = h * 48 + d;  // v/dv reshape(8,48) flat column
    const int ee0 = g2 * 8, ee1 = ee0 + 8;

    float rx = 0.f, rv0 = 0.f, rv1 = 0.f, rv2 = 0.f;
    int cur_i = i_s[ee0];
    float qv = q_ws[(size_t)cur_i * 128 + ch];

    for (int ee = ee0; ee < ee1; ee++) {
      int i = i_s[ee], j = j_s[ee];
      if (i != cur_i) {
        atomicAdd(&x_agg[(size_t)cur_i * 128 + ch], rx);
        atomicAdd(&vec_agg[(size_t)cur_i * 384 + ch], rv0);
        atomicAdd(&vec_agg[(size_t)cur_i * 384 + 128 + ch], rv1);
        atomicAdd(&vec_agg[(size_t)cur_i * 384 + 256 + ch], rv2);
        rx = rv0 = rv1 = rv2 = 0.f;
        cur_i = i;
        qv = q_ws[(size_t)i * 128 + ch];
      }
      float ddk = dkv_s[ee][ch];
      float kv = k_ws[(size_t)j * 128 + ch];
      float p = qv * kv * ddk;
      p += __shfl_xor(p, 1);
      p += __shfl_xor(p, 2);
      p += __shfl_xor(p, 4);
      p += __shfl_xor(p, 8);
      float a = silu_f(p) * cut_s[ee];
      float dv0 = dkv_s[ee][128 + vcol];
      float dv1 = dkv_s[ee][128 + vcol + 16];
      float dv2 = dkv_s[ee][128 + vcol + 32];
      const float* vr = &v_ws[(size_t)j * 384];
      float v0 = vr[vcol], v1 = vr[vcol + 16], v2 = vr[vcol + 32];
      rx += v0 * dv0 * a;
      float v1m = v1 * dv1, v2m = v2 * dv2;
      const float* vj = &vec_in[(size_t)j * 384];
      rv0 += vj[ch] * v1m + v2m * d_s[ee][0];
      rv1 += vj[128 + ch] * v1m + v2m * d_s[ee][1];
      rv2 += vj[256 + ch] * v1m + v2m * d_s[ee][2];
    }
    atomicAdd(&x_agg[(size_t)cur_i * 128 + ch], rx);
    atomicAdd(&vec_agg[(size_t)cur_i * 384 + ch], rv0);
    atomicAdd(&vec_agg[(size_t)cur_i * 384 + 128 + ch], rv1);
    atomicAdd(&vec_agg[(size_t)cur_i * 384 + 256 + ch], rv2);
  }
}

// ================= Phase C: output projection + epilogue =====================
__global__ __launch_bounds__(256, 2) void out_kernel(
    const float* __restrict__ x_agg, const float* __restrict__ ow,
    const float* __restrict__ ob, const float* __restrict__ vdot,
    const float* __restrict__ vec3, const float* __restrict__ vec_agg,
    float* __restrict__ dx, float* __restrict__ dvec) {
  __shared__ float xs[16][128];
  const int t = threadIdx.x;
  const int ch = t & 127, g = t >> 7;
  const int node0 = blockIdx.x * 16;

  for (int idx = t; idx < 16 * 128; idx += 256) {
    int n = idx >> 7, c = idx & 127;
    xs[n][c] = x_agg[(size_t)(node0 + n) * 128 + c];
  }
  __syncthreads();

  float a1[8] = {0, 0, 0, 0, 0, 0, 0, 0};
  float a2[8] = {0, 0, 0, 0, 0, 0, 0, 0};
  float a3[8] = {0, 0, 0, 0, 0, 0, 0, 0};
  gemm8x3<128>(ow + ch, ow + 128 + ch, ow + 256 + ch, 384, &xs[0][0], 128,
               g * 8, a1, a2, a3);
  float b1v = ob[ch], b2v = ob[128 + ch], b3v = ob[256 + ch];
#pragma unroll
  for (int n = 0; n < 8; n++) {
    int node = node0 + g * 8 + n;
    float o1 = a1[n] + b1v, o2 = a2[n] + b2v, o3 = a3[n] + b3v;
    dx[(size_t)node * 128 + ch] = vdot[(size_t)node * 128 + ch] * o2 + o3;
#pragma unroll
    for (int c = 0; c < 3; c++) {
      size_t off = (size_t)node * 384 + c * 128 + ch;
      dvec[off] = vec3[off] * o1 + vec_agg[off];
    }
  }
}

extern "C" void kernel_launch(void* const* d_in, const int* in_sizes, int n_in,
                              void* d_out, int out_size, void* d_ws,
                              size_t ws_size, hipStream_t stream) {
  const float* x = (const float*)d_in[0];
  const float* vec = (const float*)d_in[1];
  const float* na = (const float*)d_in[2];
  const int* ei = (const int*)d_in[3];
  const float* r_ij = (const float*)d_in[4];
  const float* f_ij = (const float*)d_in[5];
  const float* d_ijp = (const float*)d_in[6];
  const float* w1 = (const float*)d_in[7];
  const float* b1 = (const float*)d_in[8];
  const float* w2 = (const float*)d_in[9];
  const float* b2 = (const float*)d_in[10];
  const float* lng = (const float*)d_in[11];
  const float* lnb = (const float*)d_in[12];
  const float* qw = (const float*)d_in[13];
  const float* qb = (const float*)d_in[14];
  const float* kw = (const float*)d_in[15];
  const float* kb = (const float*)d_in[16];
  const float* vw = (const float*)d_in[17];
  const float* vb = (const float*)d_in[18];
  const float* ow = (const float*)d_in[19];
  const float* ob = (const float*)d_in[20];
  const float* vecw = (const float*)d_in[21];
  const float* dkw = (const float*)d_in[22];
  const float* dkb = (const float*)d_in[23];
  const float* dvw = (const float*)d_in[24];
  const float* dvb = (const float*)d_in[25];

  float* ws = (float*)d_ws;
  const size_t NH = (size_t)N_NODES * 128;
  const size_t NH3 = (size_t)N_NODES * 384;
  float* q_o = ws;                 // N*H
  float* k_o = q_o + NH;           // N*H
  float* v_o = k_o + NH;           // N*3H
  float* vdot_o = v_o + NH3;       // N*H
  float* vec3_o = vdot_o + NH;     // N*3H
  float* x_agg = vec3_o + NH3;     // N*H
  float* vec_agg = x_agg + NH;     // N*3H
  int* ibuf = (int*)(vec_agg + NH3);
  int* counts = ibuf;              // N
  int* cursor = counts + N_NODES;  // N
  int* offsets = cursor + N_NODES; // N
  int* perm = offsets + N_NODES;   // E

  hipMemsetAsync(x_agg, 0, (NH + NH3) * sizeof(float), stream);
  hipMemsetAsync(counts, 0, 2 * N_NODES * sizeof(int), stream);

  node_kernel<<<N_NODES / 16, 256, 0, stream>>>(
      x, vec, na, w1, b1, w2, b2, lng, lnb, qw, qb, kw, kb, vw, vb, vecw, q_o,
      k_o, v_o, vdot_o, vec3_o);

  hist_kernel<<<(N_EDGES + 255) / 256, 256, 0, stream>>>(ei, counts);
  scan_kernel<<<1, 1024, 0, stream>>>(counts, offsets);
  scatter_kernel<<<(N_EDGES + 255) / 256, 256, 0, stream>>>(ei, offsets, cursor,
                                                            perm);

  edge_kernel<<<N_EDGES / TILE, 256, 0, stream>>>(
      ei, perm, r_ij, f_ij, d_ijp, dkw, dkb, dvw, dvb, q_o, k_o, v_o, vec,
      x_agg, vec_agg);

  float* dx = (float*)d_out;
  float* dvec = dx + NH;
  out_kernel<<<N_NODES / 16, 256, 0, stream>>>(x_agg, ow, ob, vdot_o, vec3_o,
                                               vec_agg, dx, dvec);
}

// Round 4
// 660.374 us; speedup vs baseline: 1.6095x; 1.3204x over previous
//
#include <hip/hip_runtime.h>
#include <hip/hip_bf16.h>

#define N_NODES 20000
#define N_EDGES 200000
#define TILE 16
// H = 128, 3H = 384, RBF = 64, HEADS = 8, HD = 16

typedef __attribute__((ext_vector_type(8))) short short8;
typedef __attribute__((ext_vector_type(4))) float f32x4;

__device__ __forceinline__ float silu_f(float x) { return x / (1.f + __expf(-x)); }

__device__ __forceinline__ unsigned short f2bf(float x) {
  __hip_bfloat16 h = __float2bfloat16(x);
  return *(unsigned short*)&h;
}
__device__ __forceinline__ float bf2f(unsigned short u) {
  __hip_bfloat16 h;
  *(unsigned short*)&h = u;
  return __bfloat162float(h);
}

// ---- register-tiled helper: 8 rows x 1 col, K = KDIM ----
template <int KDIM>
__device__ __forceinline__ void gemm8(const float* __restrict__ w, int wstride,
                                      const float* src, int srcstride, int row0,
                                      float acc[8]) {
  for (int k = 0; k < KDIM; k += 4) {
    float w0 = w[(k + 0) * wstride];
    float w1 = w[(k + 1) * wstride];
    float w2 = w[(k + 2) * wstride];
    float w3 = w[(k + 3) * wstride];
#pragma unroll
    for (int n = 0; n < 8; n++) {
      const float4 a = *(const float4*)(src + (row0 + n) * srcstride + k);
      acc[n] = fmaf(a.x, w0, acc[n]);
      acc[n] = fmaf(a.y, w1, acc[n]);
      acc[n] = fmaf(a.z, w2, acc[n]);
      acc[n] = fmaf(a.w, w3, acc[n]);
    }
  }
}

template <int KDIM>
__device__ __forceinline__ void gemm8x3(const float* __restrict__ wA,
                                        const float* __restrict__ wB,
                                        const float* __restrict__ wC, int wstride,
                                        const float* src, int srcstride, int row0,
                                        float a1[8], float a2[8], float a3[8]) {
  for (int k = 0; k < KDIM; k += 4) {
    float uA0 = wA[(k + 0) * wstride], uA1 = wA[(k + 1) * wstride];
    float uA2 = wA[(k + 2) * wstride], uA3 = wA[(k + 3) * wstride];
    float uB0 = wB[(k + 0) * wstride], uB1 = wB[(k + 1) * wstride];
    float uB2 = wB[(k + 2) * wstride], uB3 = wB[(k + 3) * wstride];
    float uC0 = wC[(k + 0) * wstride], uC1 = wC[(k + 1) * wstride];
    float uC2 = wC[(k + 2) * wstride], uC3 = wC[(k + 3) * wstride];
#pragma unroll
    for (int n = 0; n < 8; n++) {
      const float4 a = *(const float4*)(src + (row0 + n) * srcstride + k);
      a1[n] = fmaf(a.x, uA0, a1[n]); a1[n] = fmaf(a.y, uA1, a1[n]);
      a1[n] = fmaf(a.z, uA2, a1[n]); a1[n] = fmaf(a.w, uA3, a1[n]);
      a2[n] = fmaf(a.x, uB0, a2[n]); a2[n] = fmaf(a.y, uB1, a2[n]);
      a2[n] = fmaf(a.z, uB2, a2[n]); a2[n] = fmaf(a.w, uB3, a2[n]);
      a3[n] = fmaf(a.x, uC0, a3[n]); a3[n] = fmaf(a.y, uC1, a3[n]);
      a3[n] = fmaf(a.z, uC2, a3[n]); a3[n] = fmaf(a.w, uC3, a3[n]);
    }
  }
}

// ========== weight pre-convert: f32 dkw/dvw -> bf16 MFMA B-fragments =========
// wfrag[((ct*2+ks)*64 + lane)*8 + i] = W[k = ks*32 + (lane>>4)*8 + i][ct*16 + (lane&15)]
// where W[k][c] = c<128 ? dkw[k*128+c] : dvw[k*384+c-128]
__global__ void wcvt_kernel(const float* __restrict__ dkw,
                            const float* __restrict__ dkb,
                            const float* __restrict__ dvw,
                            const float* __restrict__ dvb,
                            unsigned short* __restrict__ wfrag,
                            float* __restrict__ bias512) {
  int gid = blockIdx.x * 256 + threadIdx.x;
  if (gid < 32768) {
    int i = gid & 7;
    int l = (gid >> 3) & 63;
    int ks = (gid >> 9) & 1;
    int ct = gid >> 10;
    int k = ks * 32 + ((l >> 4) * 8) + i;
    int col = ct * 16 + (l & 15);
    float v = (col < 128) ? dkw[k * 128 + col] : dvw[k * 384 + (col - 128)];
    wfrag[gid] = f2bf(v);
  }
  if (gid < 512)
    bias512[gid] = (gid < 128) ? dkb[gid] : dvb[gid - 128];
}

// ================= CSR build: histogram -> parallel offsets -> scatter =======
__global__ void hist_kernel(const int* __restrict__ ei, int* __restrict__ counts) {
  int e = blockIdx.x * 256 + threadIdx.x;
  if (e < N_EDGES) atomicAdd(&counts[ei[N_EDGES + e]], 1);
}

// group order arbitrary (grouping is all the edge kernel needs)
__global__ void assign_kernel(const int* __restrict__ counts,
                              int* __restrict__ total, int* __restrict__ offsets) {
  int n = blockIdx.x * 256 + threadIdx.x;
  if (n < N_NODES) offsets[n] = atomicAdd(total, counts[n]);
}

__global__ void scatter_kernel(const int* __restrict__ ei,
                               const int* __restrict__ offsets,
                               int* __restrict__ cursor, int* __restrict__ perm) {
  int e = blockIdx.x * 256 + threadIdx.x;
  if (e < N_EDGES) {
    int i = ei[N_EDGES + e];
    int slot = atomicAdd(&cursor[i], 1);
    perm[offsets[i] + slot] = e;
  }
}

// ================= Phase A: node MLP + LN + QKV + vec einsum =================
__global__ __launch_bounds__(256, 2) void node_kernel(
    const float* __restrict__ x, const float* __restrict__ vec,
    const float* __restrict__ na, const float* __restrict__ w1,
    const float* __restrict__ b1, const float* __restrict__ w2,
    const float* __restrict__ b2, const float* __restrict__ lng,
    const float* __restrict__ lnb, const float* __restrict__ qw,
    const float* __restrict__ qb, const float* __restrict__ kw,
    const float* __restrict__ kb, const float* __restrict__ vw,
    const float* __restrict__ vb, const float* __restrict__ vecw,
    float* __restrict__ q_o, float* __restrict__ k_o, float* __restrict__ v_o,
    float* __restrict__ vdot_o, float* __restrict__ vec3_o) {
  __shared__ float in_s[16][256];
  __shared__ float vec_s[16][384];
  __shared__ float h1_s[16][128];
  __shared__ float h_s[16][128];

  const int t = threadIdx.x;
  const int ch = t & 127, g = t >> 7;
  const int node0 = blockIdx.x * 16;

  for (int idx = t; idx < 16 * 256; idx += 256) {
    int n = idx >> 8, c = idx & 255;
    in_s[n][c] = (c < 128) ? x[(node0 + n) * 128 + c]
                           : na[(node0 + n) * 128 + (c - 128)];
  }
  for (int idx = t; idx < 16 * 384; idx += 256) {
    int n = idx / 384, r = idx - n * 384;
    vec_s[n][r] = vec[(node0 + n) * 384 + r];
  }
  __syncthreads();

  {
    float acc[8] = {0, 0, 0, 0, 0, 0, 0, 0};
    gemm8<256>(w1 + ch, 128, &in_s[0][0], 256, g * 8, acc);
    float bb = b1[ch];
#pragma unroll
    for (int n = 0; n < 8; n++) h1_s[g * 8 + n][ch] = silu_f(acc[n] + bb);
  }
  __syncthreads();

  {
    float acc[8] = {0, 0, 0, 0, 0, 0, 0, 0};
    gemm8<128>(w2 + ch, 128, &h1_s[0][0], 128, g * 8, acc);
    float bb = b2[ch];
#pragma unroll
    for (int n = 0; n < 8; n++) h_s[g * 8 + n][ch] = acc[n] + bb;
  }
  __syncthreads();

  {
    int wave = t >> 6, lane = t & 63;
    for (int nn = wave * 4; nn < wave * 4 + 4; nn++) {
      float v0 = h_s[nn][lane], v1 = h_s[nn][64 + lane];
      float s = v0 + v1, ss = v0 * v0 + v1 * v1;
#pragma unroll
      for (int m = 1; m < 64; m <<= 1) {
        s += __shfl_xor(s, m);
        ss += __shfl_xor(ss, m);
      }
      float mean = s * (1.f / 128.f);
      float var = ss * (1.f / 128.f) - mean * mean;
      float rs = rsqrtf(var + 1e-5f);
      h_s[nn][lane] = (v0 - mean) * rs * lng[lane] + lnb[lane];
      h_s[nn][64 + lane] = (v1 - mean) * rs * lng[64 + lane] + lnb[64 + lane];
    }
  }
  __syncthreads();

#pragma unroll
  for (int cb = 0; cb < 5; cb++) {
    const float* wsel;
    const float* bsel;
    float* osel;
    int wstr, ostr;
    if (cb == 0) { wsel = qw + ch; bsel = qb + ch; osel = q_o + ch; wstr = 128; ostr = 128; }
    else if (cb == 1) { wsel = kw + ch; bsel = kb + ch; osel = k_o + ch; wstr = 128; ostr = 128; }
    else { int cc = (cb - 2) * 128 + ch; wsel = vw + cc; bsel = vb + cc; osel = v_o + cc; wstr = 384; ostr = 384; }
    float acc[8] = {0, 0, 0, 0, 0, 0, 0, 0};
    gemm8<128>(wsel, wstr, &h_s[0][0], 128, g * 8, acc);
    float bb = *bsel;
#pragma unroll
    for (int n = 0; n < 8; n++) osel[(size_t)(node0 + g * 8 + n) * ostr] = acc[n] + bb;
  }

  {
    float vdot[8] = {0, 0, 0, 0, 0, 0, 0, 0};
#pragma unroll
    for (int c = 0; c < 3; c++) {
      float a1[8] = {0, 0, 0, 0, 0, 0, 0, 0};
      float a2[8] = {0, 0, 0, 0, 0, 0, 0, 0};
      float a3[8] = {0, 0, 0, 0, 0, 0, 0, 0};
      gemm8x3<128>(vecw + ch, vecw + 128 + ch, vecw + 256 + ch, 384,
                   &vec_s[0][c * 128], 384, g * 8, a1, a2, a3);
#pragma unroll
      for (int n = 0; n < 8; n++) {
        vdot[n] += a1[n] * a2[n];
        vec3_o[(size_t)(node0 + g * 8 + n) * 384 + c * 128 + ch] = a3[n];
      }
    }
#pragma unroll
    for (int n = 0; n < 8; n++)
      vdot_o[(size_t)(node0 + g * 8 + n) * 128 + ch] = vdot[n];
  }
}

// ====== Phase B: MFMA dkv GEMM + attention + run-accumulated scatter =========
__global__ __launch_bounds__(256, 6) void edge_kernel(
    const int* __restrict__ ei, const int* __restrict__ perm,
    const float* __restrict__ r_ij, const float* __restrict__ f_ij,
    const float* __restrict__ d_ij, const unsigned short* __restrict__ wfrag,
    const float* __restrict__ bias512, const float* __restrict__ q_ws,
    const float* __restrict__ k_ws, const float* __restrict__ v_ws,
    const float* __restrict__ vec_in, float* __restrict__ x_agg,
    float* __restrict__ vec_agg) {
  __shared__ unsigned short f_s[TILE][72];     // bf16, row stride 144B (16B mult)
  __shared__ unsigned short dkv_s[TILE][520];  // bf16
  __shared__ int j_s[TILE];
  __shared__ int i_s[TILE];
  __shared__ float cut_s[TILE];
  __shared__ float d_s[TILE][3];

  const int t = threadIdx.x;
  const int e0 = blockIdx.x * TILE;

  // ---- stage edge metadata (sorted order via perm) ----
  if (t < TILE) {
    int e = perm[e0 + t];
    j_s[t] = ei[e];
    i_s[t] = ei[N_EDGES + e];
    float r = r_ij[e];
    cut_s[t] = 0.5f * (__cosf(r * 0.31415926535f) + 1.f) * (r < 10.f ? 1.f : 0.f);
    d_s[t][0] = d_ij[e * 3 + 0];
    d_s[t][1] = d_ij[e * 3 + 1];
    d_s[t][2] = d_ij[e * 3 + 2];
  }
  // ---- stage f tile as bf16: 16 rows x 64, 8 threads/row ----
  if (t < 128) {
    int row = t >> 3, c0 = (t & 7) * 8;
    int e = perm[e0 + row];
    const float4* src = (const float4*)&f_ij[(size_t)e * 64 + c0];
    float4 v0 = src[0], v1 = src[1];
    uint4 pk;
    pk.x = (unsigned)f2bf(v0.x) | ((unsigned)f2bf(v0.y) << 16);
    pk.y = (unsigned)f2bf(v0.z) | ((unsigned)f2bf(v0.w) << 16);
    pk.z = (unsigned)f2bf(v1.x) | ((unsigned)f2bf(v1.y) << 16);
    pk.w = (unsigned)f2bf(v1.z) | ((unsigned)f2bf(v1.w) << 16);
    *(uint4*)&f_s[row][c0] = pk;
  }
  __syncthreads();

  // ---- dkv GEMM via MFMA 16x16x32 bf16: [16,64] @ [64,512] -> dkv_s ----
  {
    const int lane = t & 63, wave = t >> 6;
    const unsigned short* arow = &f_s[lane & 15][(lane >> 4) * 8];
    short8 a0 = *(const short8*)arow;          // k = (lane>>4)*8 + i
    short8 a1 = *(const short8*)(arow + 32);   // k = 32 + ...
#pragma unroll
    for (int c = 0; c < 8; c++) {
      int ct = wave * 8 + c;
      short8 b0 = *(const short8*)(wfrag + ((size_t)(ct * 2 + 0) * 64 + lane) * 8);
      short8 b1 = *(const short8*)(wfrag + ((size_t)(ct * 2 + 1) * 64 + lane) * 8);
      f32x4 acc = {0.f, 0.f, 0.f, 0.f};
      acc = __builtin_amdgcn_mfma_f32_16x16x32_bf16(a0, b0, acc, 0, 0, 0);
      acc = __builtin_amdgcn_mfma_f32_16x16x32_bf16(a1, b1, acc, 0, 0, 0);
      int col = ct * 16 + (lane & 15);
      float bb = bias512[col];
#pragma unroll
      for (int r = 0; r < 4; r++) {
        int eg = (lane >> 4) * 4 + r;  // D row = edge
        dkv_s[eg][col] = f2bf(silu_f(acc[r] + bb));
      }
    }
  }
  __syncthreads();

  // ---- attention + messages + run-accumulated scatter ----
  {
    const int ch = t & 127, g2 = t >> 7;
    const int h = ch >> 4, d = ch & 15;
    const int vcol = h * 48 + d;  // v/dv reshape(8,48) flat column
    const int ee0 = g2 * 8, ee1 = ee0 + 8;

    float rx = 0.f, rv0 = 0.f, rv1 = 0.f, rv2 = 0.f;
    int cur_i = i_s[ee0];
    float qv = q_ws[(size_t)cur_i * 128 + ch];

    for (int ee = ee0; ee < ee1; ee++) {
      int i = i_s[ee], j = j_s[ee];
      if (i != cur_i) {
        atomicAdd(&x_agg[(size_t)cur_i * 128 + ch], rx);
        atomicAdd(&vec_agg[(size_t)cur_i * 384 + ch], rv0);
        atomicAdd(&vec_agg[(size_t)cur_i * 384 + 128 + ch], rv1);
        atomicAdd(&vec_agg[(size_t)cur_i * 384 + 256 + ch], rv2);
        rx = rv0 = rv1 = rv2 = 0.f;
        cur_i = i;
        qv = q_ws[(size_t)i * 128 + ch];
      }
      float ddk = bf2f(dkv_s[ee][ch]);
      float kv = k_ws[(size_t)j * 128 + ch];
      float p = qv * kv * ddk;
      p += __shfl_xor(p, 1);
      p += __shfl_xor(p, 2);
      p += __shfl_xor(p, 4);
      p += __shfl_xor(p, 8);
      float a = silu_f(p) * cut_s[ee];
      float dv0 = bf2f(dkv_s[ee][128 + vcol]);
      float dv1 = bf2f(dkv_s[ee][128 + vcol + 16]);
      float dv2 = bf2f(dkv_s[ee][128 + vcol + 32]);
      const float* vr = &v_ws[(size_t)j * 384];
      float v0 = vr[vcol], v1 = vr[vcol + 16], v2 = vr[vcol + 32];
      rx += v0 * dv0 * a;
      float v1m = v1 * dv1, v2m = v2 * dv2;
      const float* vj = &vec_in[(size_t)j * 384];
      rv0 += vj[ch] * v1m + v2m * d_s[ee][0];
      rv1 += vj[128 + ch] * v1m + v2m * d_s[ee][1];
      rv2 += vj[256 + ch] * v1m + v2m * d_s[ee][2];
    }
    atomicAdd(&x_agg[(size_t)cur_i * 128 + ch], rx);
    atomicAdd(&vec_agg[(size_t)cur_i * 384 + ch], rv0);
    atomicAdd(&vec_agg[(size_t)cur_i * 384 + 128 + ch], rv1);
    atomicAdd(&vec_agg[(size_t)cur_i * 384 + 256 + ch], rv2);
  }
}

// ================= Phase C: output projection + epilogue =====================
__global__ __launch_bounds__(256, 2) void out_kernel(
    const float* __restrict__ x_agg, const float* __restrict__ ow,
    const float* __restrict__ ob, const float* __restrict__ vdot,
    const float* __restrict__ vec3, const float* __restrict__ vec_agg,
    float* __restrict__ dx, float* __restrict__ dvec) {
  __shared__ float xs[16][128];
  const int t = threadIdx.x;
  const int ch = t & 127, g = t >> 7;
  const int node0 = blockIdx.x * 16;

  for (int idx = t; idx < 16 * 128; idx += 256) {
    int n = idx >> 7, c = idx & 127;
    xs[n][c] = x_agg[(size_t)(node0 + n) * 128 + c];
  }
  __syncthreads();

  float a1[8] = {0, 0, 0, 0, 0, 0, 0, 0};
  float a2[8] = {0, 0, 0, 0, 0, 0, 0, 0};
  float a3[8] = {0, 0, 0, 0, 0, 0, 0, 0};
  gemm8x3<128>(ow + ch, ow + 128 + ch, ow + 256 + ch, 384, &xs[0][0], 128,
               g * 8, a1, a2, a3);
  float b1v = ob[ch], b2v = ob[128 + ch], b3v = ob[256 + ch];
#pragma unroll
  for (int n = 0; n < 8; n++) {
    int node = node0 + g * 8 + n;
    float o1 = a1[n] + b1v, o2 = a2[n] + b2v, o3 = a3[n] + b3v;
    dx[(size_t)node * 128 + ch] = vdot[(size_t)node * 128 + ch] * o2 + o3;
#pragma unroll
    for (int c = 0; c < 3; c++) {
      size_t off = (size_t)node * 384 + c * 128 + ch;
      dvec[off] = vec3[off] * o1 + vec_agg[off];
    }
  }
}

extern "C" void kernel_launch(void* const* d_in, const int* in_sizes, int n_in,
                              void* d_out, int out_size, void* d_ws,
                              size_t ws_size, hipStream_t stream) {
  const float* x = (const float*)d_in[0];
  const float* vec = (const float*)d_in[1];
  const float* na = (const float*)d_in[2];
  const int* ei = (const int*)d_in[3];
  const float* r_ij = (const float*)d_in[4];
  const float* f_ij = (const float*)d_in[5];
  const float* d_ijp = (const float*)d_in[6];
  const float* w1 = (const float*)d_in[7];
  const float* b1 = (const float*)d_in[8];
  const float* w2 = (const float*)d_in[9];
  const float* b2 = (const float*)d_in[10];
  const float* lng = (const float*)d_in[11];
  const float* lnb = (const float*)d_in[12];
  const float* qw = (const float*)d_in[13];
  const float* qb = (const float*)d_in[14];
  const float* kw = (const float*)d_in[15];
  const float* kb = (const float*)d_in[16];
  const float* vw = (const float*)d_in[17];
  const float* vb = (const float*)d_in[18];
  const float* ow = (const float*)d_in[19];
  const float* ob = (const float*)d_in[20];
  const float* vecw = (const float*)d_in[21];
  const float* dkw = (const float*)d_in[22];
  const float* dkb = (const float*)d_in[23];
  const float* dvw = (const float*)d_in[24];
  const float* dvb = (const float*)d_in[25];

  float* ws = (float*)d_ws;
  const size_t NH = (size_t)N_NODES * 128;
  const size_t NH3 = (size_t)N_NODES * 384;
  float* q_o = ws;                 // N*H
  float* k_o = q_o + NH;           // N*H
  float* v_o = k_o + NH;           // N*3H
  float* vdot_o = v_o + NH3;       // N*H
  float* vec3_o = vdot_o + NH;     // N*3H
  float* x_agg = vec3_o + NH3;     // N*H
  float* vec_agg = x_agg + NH;     // N*3H
  // 16B-aligned region for bf16 weight fragments (32768 ushort = 16384 floats)
  unsigned short* wfrag = (unsigned short*)(vec_agg + NH3);
  float* bias512 = (float*)(wfrag + 32768);  // 512 floats
  int* ibuf = (int*)(bias512 + 512);
  int* counts = ibuf;              // N
  int* cursor = counts + N_NODES;  // N
  int* total = cursor + N_NODES;   // 1
  int* offsets = total + 1;        // N
  int* perm = offsets + N_NODES;   // E

  hipMemsetAsync(x_agg, 0, (NH + NH3) * sizeof(float), stream);
  hipMemsetAsync(counts, 0, (2 * N_NODES + 1) * sizeof(int), stream);

  wcvt_kernel<<<128, 256, 0, stream>>>(dkw, dkb, dvw, dvb, wfrag, bias512);

  node_kernel<<<N_NODES / 16, 256, 0, stream>>>(
      x, vec, na, w1, b1, w2, b2, lng, lnb, qw, qb, kw, kb, vw, vb, vecw, q_o,
      k_o, v_o, vdot_o, vec3_o);

  hist_kernel<<<(N_EDGES + 255) / 256, 256, 0, stream>>>(ei, counts);
  assign_kernel<<<(N_NODES + 255) / 256, 256, 0, stream>>>(counts, total,
                                                           offsets);
  scatter_kernel<<<(N_EDGES + 255) / 256, 256, 0, stream>>>(ei, offsets, cursor,
                                                            perm);

  edge_kernel<<<N_EDGES / TILE, 256, 0, stream>>>(
      ei, perm, r_ij, f_ij, d_ijp, wfrag, bias512, q_o, k_o, v_o, vec, x_agg,
      vec_agg);

  float* dx = (float*)d_out;
  float* dvec = dx + NH;
  out_kernel<<<N_NODES / 16, 256, 0, stream>>>(x_agg, ow, ob, vdot_o, vec3_o,
                                               vec_agg, dx, dvec);
}

// Round 5
// 458.021 us; speedup vs baseline: 2.3205x; 1.4418x over previous
//
#include <hip/hip_runtime.h>
#include <hip/hip_bf16.h>

#define N_NODES 20000
#define N_EDGES 200000
#define TILE 16
// H = 128, 3H = 384, RBF = 64, HEADS = 8, HD = 16

typedef __attribute__((ext_vector_type(8))) short short8;
typedef __attribute__((ext_vector_type(4))) float f32x4;

__device__ __forceinline__ float silu_f(float x) { return x / (1.f + __expf(-x)); }

__device__ __forceinline__ unsigned short f2bf(float x) {
  __hip_bfloat16 h = __float2bfloat16(x);
  return *(unsigned short*)&h;
}
__device__ __forceinline__ float bf2f(unsigned short u) {
  __hip_bfloat16 h;
  *(unsigned short*)&h = u;
  return __bfloat162float(h);
}
__device__ __forceinline__ unsigned pk2(float a, float b) {
  return (unsigned)f2bf(a) | ((unsigned)f2bf(b) << 16);
}

// node-weight fragment base offsets (ushort units)
#define W1F 0
#define W2F 32768
#define QF 49152
#define KF 65536
#define VF 81920
#define VECF 131072
#define NWF_TOTAL 180224

// ---- f32 register-tiled helper (still used by out_kernel) ----
template <int KDIM>
__device__ __forceinline__ void gemm8x3(const float* __restrict__ wA,
                                        const float* __restrict__ wB,
                                        const float* __restrict__ wC, int wstride,
                                        const float* src, int srcstride, int row0,
                                        float a1[8], float a2[8], float a3[8]) {
  for (int k = 0; k < KDIM; k += 4) {
    float uA0 = wA[(k + 0) * wstride], uA1 = wA[(k + 1) * wstride];
    float uA2 = wA[(k + 2) * wstride], uA3 = wA[(k + 3) * wstride];
    float uB0 = wB[(k + 0) * wstride], uB1 = wB[(k + 1) * wstride];
    float uB2 = wB[(k + 2) * wstride], uB3 = wB[(k + 3) * wstride];
    float uC0 = wC[(k + 0) * wstride], uC1 = wC[(k + 1) * wstride];
    float uC2 = wC[(k + 2) * wstride], uC3 = wC[(k + 3) * wstride];
#pragma unroll
    for (int n = 0; n < 8; n++) {
      const float4 a = *(const float4*)(src + (row0 + n) * srcstride + k);
      a1[n] = fmaf(a.x, uA0, a1[n]); a1[n] = fmaf(a.y, uA1, a1[n]);
      a1[n] = fmaf(a.z, uA2, a1[n]); a1[n] = fmaf(a.w, uA3, a1[n]);
      a2[n] = fmaf(a.x, uB0, a2[n]); a2[n] = fmaf(a.y, uB1, a2[n]);
      a2[n] = fmaf(a.z, uB2, a2[n]); a2[n] = fmaf(a.w, uB3, a2[n]);
      a3[n] = fmaf(a.x, uC0, a3[n]); a3[n] = fmaf(a.y, uC1, a3[n]);
      a3[n] = fmaf(a.z, uC2, a3[n]); a3[n] = fmaf(a.w, uC3, a3[n]);
    }
  }
}

// ========== edge-weight pre-convert: f32 dkw/dvw -> bf16 MFMA B-fragments ====
__global__ void wcvt_kernel(const float* __restrict__ dkw,
                            const float* __restrict__ dkb,
                            const float* __restrict__ dvw,
                            const float* __restrict__ dvb,
                            unsigned short* __restrict__ wfrag,
                            float* __restrict__ bias512) {
  int gid = blockIdx.x * 256 + threadIdx.x;
  if (gid < 32768) {
    int i = gid & 7;
    int l = (gid >> 3) & 63;
    int ks = (gid >> 9) & 1;
    int ct = gid >> 10;
    int k = ks * 32 + ((l >> 4) * 8) + i;
    int col = ct * 16 + (l & 15);
    float v = (col < 128) ? dkw[k * 128 + col] : dvw[k * 384 + (col - 128)];
    wfrag[gid] = f2bf(v);
  }
  if (gid < 512)
    bias512[gid] = (gid < 128) ? dkb[gid] : dvb[gid - 128];
}

// ========== node-weight pre-convert: 6 matrices -> bf16 B-fragments ==========
// frag idx = ((nt*KT + kt)*64 + lane)*8 + i ; value = W[kt*32+(lane>>4)*8+i][nt*16+(lane&15)]
__global__ void wcvt_node_kernel(const float* __restrict__ w1,
                                 const float* __restrict__ w2,
                                 const float* __restrict__ qw,
                                 const float* __restrict__ kw,
                                 const float* __restrict__ vw,
                                 const float* __restrict__ vecw,
                                 unsigned short* __restrict__ wf) {
  int gid = blockIdx.x * 256 + threadIdx.x;
  if (gid >= NWF_TOTAL) return;
  const float* W;
  int N, KT, loc;
  if (gid < 32768) { W = w1; N = 128; KT = 8; loc = gid; }
  else if (gid < 49152) { W = w2; N = 128; KT = 4; loc = gid - 32768; }
  else if (gid < 65536) { W = qw; N = 128; KT = 4; loc = gid - 49152; }
  else if (gid < 81920) { W = kw; N = 128; KT = 4; loc = gid - 65536; }
  else if (gid < 131072) { W = vw; N = 384; KT = 4; loc = gid - 81920; }
  else { W = vecw; N = 384; KT = 4; loc = gid - 131072; }
  int i = loc & 7, lane = (loc >> 3) & 63, t9 = loc >> 9;
  int kt = t9 % KT, nt = t9 / KT;
  int k = kt * 32 + ((lane >> 4) * 8) + i;
  int n = nt * 16 + (lane & 15);
  wf[gid] = f2bf(W[(size_t)k * N + n]);
}

// ================= CSR build: histogram -> parallel offsets -> scatter =======
__global__ void hist_kernel(const int* __restrict__ ei, int* __restrict__ counts) {
  int e = blockIdx.x * 256 + threadIdx.x;
  if (e < N_EDGES) atomicAdd(&counts[ei[N_EDGES + e]], 1);
}

__global__ void assign_kernel(const int* __restrict__ counts,
                              int* __restrict__ total, int* __restrict__ offsets) {
  int n = blockIdx.x * 256 + threadIdx.x;
  if (n < N_NODES) offsets[n] = atomicAdd(total, counts[n]);
}

__global__ void scatter_kernel(const int* __restrict__ ei,
                               const int* __restrict__ offsets,
                               int* __restrict__ cursor, int* __restrict__ perm) {
  int e = blockIdx.x * 256 + threadIdx.x;
  if (e < N_EDGES) {
    int i = ei[N_EDGES + e];
    int slot = atomicAdd(&cursor[i], 1);
    perm[offsets[i] + slot] = e;
  }
}

// ============ Phase A: MFMA node MLP + LN + QKV + vec einsum =================
__global__ __launch_bounds__(256, 4) void node_kernel(
    const float* __restrict__ x, const float* __restrict__ vec,
    const float* __restrict__ na, const unsigned short* __restrict__ wf,
    const float* __restrict__ b1, const float* __restrict__ b2,
    const float* __restrict__ lng, const float* __restrict__ lnb,
    const float* __restrict__ qb, const float* __restrict__ kb,
    const float* __restrict__ vb, float* __restrict__ q_o,
    float* __restrict__ k_o, float* __restrict__ v_o,
    float* __restrict__ vdot_o, float* __restrict__ vec3_o) {
  __shared__ unsigned short in_s[16][264];     // x||na bf16 (K=256), pad->528B stride
  __shared__ unsigned short vec_s[3][16][136]; // vec bf16 per channel (K=128)
  __shared__ float hf_s[16][132];              // pre-LN f32
  __shared__ unsigned short h1_s[16][136];
  __shared__ unsigned short h_s[16][136];

  const int t = threadIdx.x;
  const int lane = t & 63, w = t >> 6;
  const int node0 = blockIdx.x * 16;
  const int srow = t & 15, scg = t >> 4;
  const int arow = lane & 15, acol = (lane >> 4) * 8;
  const int drow0 = (lane >> 4) * 4;

  // ---- stage x||na (16 cols/thread) ----
  {
    const float* src = (scg < 8) ? &x[(size_t)(node0 + srow) * 128 + scg * 16]
                                 : &na[(size_t)(node0 + srow) * 128 + (scg - 8) * 16];
    float4 v0 = ((const float4*)src)[0], v1 = ((const float4*)src)[1];
    float4 v2 = ((const float4*)src)[2], v3 = ((const float4*)src)[3];
    uint4 p0, p1;
    p0.x = pk2(v0.x, v0.y); p0.y = pk2(v0.z, v0.w);
    p0.z = pk2(v1.x, v1.y); p0.w = pk2(v1.z, v1.w);
    p1.x = pk2(v2.x, v2.y); p1.y = pk2(v2.z, v2.w);
    p1.z = pk2(v3.x, v3.y); p1.w = pk2(v3.z, v3.w);
    *(uint4*)&in_s[srow][scg * 16] = p0;
    *(uint4*)&in_s[srow][scg * 16 + 8] = p1;
  }
  // ---- stage vec (8 cols/thread per channel) ----
#pragma unroll
  for (int ch = 0; ch < 3; ch++) {
    const float* src = &vec[(size_t)(node0 + srow) * 384 + ch * 128 + scg * 8];
    float4 v0 = ((const float4*)src)[0], v1 = ((const float4*)src)[1];
    uint4 p;
    p.x = pk2(v0.x, v0.y); p.y = pk2(v0.z, v0.w);
    p.z = pk2(v1.x, v1.y); p.w = pk2(v1.z, v1.w);
    *(uint4*)&vec_s[ch][srow][scg * 8] = p;
  }
  __syncthreads();

  // ---- mix GEMM1: [16,256]@[256,128] -> silu -> h1_s (bf16) ----
  {
    short8 af[8];
#pragma unroll
    for (int kt = 0; kt < 8; kt++)
      af[kt] = *(const short8*)&in_s[arow][kt * 32 + acol];
#pragma unroll
    for (int nn = 0; nn < 2; nn++) {
      int nt = w * 2 + nn;
      f32x4 acc = {0.f, 0.f, 0.f, 0.f};
#pragma unroll
      for (int kt = 0; kt < 8; kt++)
        acc = __builtin_amdgcn_mfma_f32_16x16x32_bf16(
            af[kt], *(const short8*)(wf + W1F + ((size_t)(nt * 8 + kt) * 64 + lane) * 8),
            acc, 0, 0, 0);
      int col = nt * 16 + (lane & 15);
      float bb = b1[col];
#pragma unroll
      for (int r = 0; r < 4; r++)
        h1_s[drow0 + r][col] = f2bf(silu_f(acc[r] + bb));
    }
  }
  __syncthreads();

  // ---- mix GEMM2: [16,128]@[128,128] -> hf_s (f32 pre-LN) ----
  {
    short8 ah1[4];
#pragma unroll
    for (int kt = 0; kt < 4; kt++)
      ah1[kt] = *(const short8*)&h1_s[arow][kt * 32 + acol];
#pragma unroll
    for (int nn = 0; nn < 2; nn++) {
      int nt = w * 2 + nn;
      f32x4 acc = {0.f, 0.f, 0.f, 0.f};
#pragma unroll
      for (int kt = 0; kt < 4; kt++)
        acc = __builtin_amdgcn_mfma_f32_16x16x32_bf16(
            ah1[kt], *(const short8*)(wf + W2F + ((size_t)(nt * 4 + kt) * 64 + lane) * 8),
            acc, 0, 0, 0);
      int col = nt * 16 + (lane & 15);
      float bb = b2[col];
#pragma unroll
      for (int r = 0; r < 4; r++) hf_s[drow0 + r][col] = acc[r] + bb;
    }
  }
  __syncthreads();

  // ---- LayerNorm (f32) -> h_s (bf16) ----
  {
    float lg0 = lng[lane], lg1 = lng[64 + lane];
    float lb0 = lnb[lane], lb1 = lnb[64 + lane];
    for (int nn = w * 4; nn < w * 4 + 4; nn++) {
      float v0 = hf_s[nn][lane], v1 = hf_s[nn][64 + lane];
      float s = v0 + v1, ss = v0 * v0 + v1 * v1;
#pragma unroll
      for (int m = 1; m < 64; m <<= 1) {
        s += __shfl_xor(s, m);
        ss += __shfl_xor(ss, m);
      }
      float mean = s * (1.f / 128.f);
      float var = ss * (1.f / 128.f) - mean * mean;
      float rs = rsqrtf(var + 1e-5f);
      h_s[nn][lane] = f2bf((v0 - mean) * rs * lg0 + lb0);
      h_s[nn][64 + lane] = f2bf((v1 - mean) * rs * lg1 + lb1);
    }
  }
  __syncthreads();

  // ---- q/k/v projections: 40 column-tiles over 4 waves ----
  {
    short8 ah[4];
#pragma unroll
    for (int kt = 0; kt < 4; kt++)
      ah[kt] = *(const short8*)&h_s[arow][kt * 32 + acol];
    for (int u = 0; u < 10; u++) {
      int idx = w * 10 + u;
      int nt, base, ost;
      const float* bias;
      float* outp;
      if (idx < 8) { nt = idx; base = QF; bias = qb; outp = q_o; ost = 128; }
      else if (idx < 16) { nt = idx - 8; base = KF; bias = kb; outp = k_o; ost = 128; }
      else { nt = idx - 16; base = VF; bias = vb; outp = v_o; ost = 384; }
      f32x4 acc = {0.f, 0.f, 0.f, 0.f};
#pragma unroll
      for (int kt = 0; kt < 4; kt++)
        acc = __builtin_amdgcn_mfma_f32_16x16x32_bf16(
            ah[kt], *(const short8*)(wf + base + ((size_t)(nt * 4 + kt) * 64 + lane) * 8),
            acc, 0, 0, 0);
      int col = nt * 16 + (lane & 15);
      float bv = bias[col];
#pragma unroll
      for (int r = 0; r < 4; r++)
        outp[(size_t)(node0 + drow0 + r) * ost + col] = acc[r] + bv;
    }
  }

  // ---- vec einsum: vp = vec@vecw ; vdot = sum_c vp1*vp2 ; store vp3 ----
  {
    f32x4 vd0 = {0.f, 0.f, 0.f, 0.f}, vd1 = {0.f, 0.f, 0.f, 0.f};
#pragma unroll
    for (int ch = 0; ch < 3; ch++) {
      short8 av[4];
#pragma unroll
      for (int kt = 0; kt < 4; kt++)
        av[kt] = *(const short8*)&vec_s[ch][arow][kt * 32 + acol];
#pragma unroll
      for (int nn = 0; nn < 2; nn++) {
        int nt1 = w * 2 + nn, nt2 = 8 + w * 2 + nn, nt3 = 16 + w * 2 + nn;
        f32x4 p1 = {0.f, 0.f, 0.f, 0.f}, p2 = {0.f, 0.f, 0.f, 0.f},
              p3 = {0.f, 0.f, 0.f, 0.f};
#pragma unroll
        for (int kt = 0; kt < 4; kt++) {
          p1 = __builtin_amdgcn_mfma_f32_16x16x32_bf16(
              av[kt], *(const short8*)(wf + VECF + ((size_t)(nt1 * 4 + kt) * 64 + lane) * 8),
              p1, 0, 0, 0);
          p2 = __builtin_amdgcn_mfma_f32_16x16x32_bf16(
              av[kt], *(const short8*)(wf + VECF + ((size_t)(nt2 * 4 + kt) * 64 + lane) * 8),
              p2, 0, 0, 0);
          p3 = __builtin_amdgcn_mfma_f32_16x16x32_bf16(
              av[kt], *(const short8*)(wf + VECF + ((size_t)(nt3 * 4 + kt) * 64 + lane) * 8),
              p3, 0, 0, 0);
        }
        if (nn == 0) vd0 += p1 * p2; else vd1 += p1 * p2;
        int col = (w * 2 + nn) * 16 + (lane & 15);
#pragma unroll
        for (int r = 0; r < 4; r++)
          vec3_o[(size_t)(node0 + drow0 + r) * 384 + ch * 128 + col] = p3[r];
      }
    }
#pragma unroll
    for (int nn = 0; nn < 2; nn++) {
      int col = (w * 2 + nn) * 16 + (lane & 15);
      f32x4 vd = (nn == 0) ? vd0 : vd1;
#pragma unroll
      for (int r = 0; r < 4; r++)
        vdot_o[(size_t)(node0 + drow0 + r) * 128 + col] = vd[r];
    }
  }
}

// ====== Phase B: MFMA dkv GEMM + attention + run-accumulated scatter =========
__global__ __launch_bounds__(256, 6) void edge_kernel(
    const int* __restrict__ ei, const int* __restrict__ perm,
    const float* __restrict__ r_ij, const float* __restrict__ f_ij,
    const float* __restrict__ d_ij, const unsigned short* __restrict__ wfrag,
    const float* __restrict__ bias512, const float* __restrict__ q_ws,
    const float* __restrict__ k_ws, const float* __restrict__ v_ws,
    const float* __restrict__ vec_in, float* __restrict__ x_agg,
    float* __restrict__ vec_agg) {
  __shared__ unsigned short f_s[TILE][72];
  __shared__ unsigned short dkv_s[TILE][520];
  __shared__ int j_s[TILE];
  __shared__ int i_s[TILE];
  __shared__ float cut_s[TILE];
  __shared__ float d_s[TILE][3];

  const int t = threadIdx.x;
  const int e0 = blockIdx.x * TILE;

  if (t < TILE) {
    int e = perm[e0 + t];
    j_s[t] = ei[e];
    i_s[t] = ei[N_EDGES + e];
    float r = r_ij[e];
    cut_s[t] = 0.5f * (__cosf(r * 0.31415926535f) + 1.f) * (r < 10.f ? 1.f : 0.f);
    d_s[t][0] = d_ij[e * 3 + 0];
    d_s[t][1] = d_ij[e * 3 + 1];
    d_s[t][2] = d_ij[e * 3 + 2];
  }
  if (t < 128) {
    int row = t >> 3, c0 = (t & 7) * 8;
    int e = perm[e0 + row];
    const float4* src = (const float4*)&f_ij[(size_t)e * 64 + c0];
    float4 v0 = src[0], v1 = src[1];
    uint4 pk;
    pk.x = pk2(v0.x, v0.y);
    pk.y = pk2(v0.z, v0.w);
    pk.z = pk2(v1.x, v1.y);
    pk.w = pk2(v1.z, v1.w);
    *(uint4*)&f_s[row][c0] = pk;
  }
  __syncthreads();

  {
    const int lane = t & 63, wave = t >> 6;
    const unsigned short* arow = &f_s[lane & 15][(lane >> 4) * 8];
    short8 a0 = *(const short8*)arow;
    short8 a1 = *(const short8*)(arow + 32);
#pragma unroll
    for (int c = 0; c < 8; c++) {
      int ct = wave * 8 + c;
      short8 b0 = *(const short8*)(wfrag + ((size_t)(ct * 2 + 0) * 64 + lane) * 8);
      short8 b1 = *(const short8*)(wfrag + ((size_t)(ct * 2 + 1) * 64 + lane) * 8);
      f32x4 acc = {0.f, 0.f, 0.f, 0.f};
      acc = __builtin_amdgcn_mfma_f32_16x16x32_bf16(a0, b0, acc, 0, 0, 0);
      acc = __builtin_amdgcn_mfma_f32_16x16x32_bf16(a1, b1, acc, 0, 0, 0);
      int col = ct * 16 + (lane & 15);
      float bb = bias512[col];
#pragma unroll
      for (int r = 0; r < 4; r++) {
        int eg = (lane >> 4) * 4 + r;
        dkv_s[eg][col] = f2bf(silu_f(acc[r] + bb));
      }
    }
  }
  __syncthreads();

  {
    const int ch = t & 127, g2 = t >> 7;
    const int h = ch >> 4, d = ch & 15;
    const int vcol = h * 48 + d;
    const int ee0 = g2 * 8, ee1 = ee0 + 8;

    float rx = 0.f, rv0 = 0.f, rv1 = 0.f, rv2 = 0.f;
    int cur_i = i_s[ee0];
    float qv = q_ws[(size_t)cur_i * 128 + ch];

    for (int ee = ee0; ee < ee1; ee++) {
      int i = i_s[ee], j = j_s[ee];
      if (i != cur_i) {
        atomicAdd(&x_agg[(size_t)cur_i * 128 + ch], rx);
        atomicAdd(&vec_agg[(size_t)cur_i * 384 + ch], rv0);
        atomicAdd(&vec_agg[(size_t)cur_i * 384 + 128 + ch], rv1);
        atomicAdd(&vec_agg[(size_t)cur_i * 384 + 256 + ch], rv2);
        rx = rv0 = rv1 = rv2 = 0.f;
        cur_i = i;
        qv = q_ws[(size_t)i * 128 + ch];
      }
      float ddk = bf2f(dkv_s[ee][ch]);
      float kv = k_ws[(size_t)j * 128 + ch];
      float p = qv * kv * ddk;
      p += __shfl_xor(p, 1);
      p += __shfl_xor(p, 2);
      p += __shfl_xor(p, 4);
      p += __shfl_xor(p, 8);
      float a = silu_f(p) * cut_s[ee];
      float dv0 = bf2f(dkv_s[ee][128 + vcol]);
      float dv1 = bf2f(dkv_s[ee][128 + vcol + 16]);
      float dv2 = bf2f(dkv_s[ee][128 + vcol + 32]);
      const float* vr = &v_ws[(size_t)j * 384];
      float v0 = vr[vcol], v1 = vr[vcol + 16], v2 = vr[vcol + 32];
      rx += v0 * dv0 * a;
      float v1m = v1 * dv1, v2m = v2 * dv2;
      const float* vj = &vec_in[(size_t)j * 384];
      rv0 += vj[ch] * v1m + v2m * d_s[ee][0];
      rv1 += vj[128 + ch] * v1m + v2m * d_s[ee][1];
      rv2 += vj[256 + ch] * v1m + v2m * d_s[ee][2];
    }
    atomicAdd(&x_agg[(size_t)cur_i * 128 + ch], rx);
    atomicAdd(&vec_agg[(size_t)cur_i * 384 + ch], rv0);
    atomicAdd(&vec_agg[(size_t)cur_i * 384 + 128 + ch], rv1);
    atomicAdd(&vec_agg[(size_t)cur_i * 384 + 256 + ch], rv2);
  }
}

// ================= Phase C: output projection + epilogue =====================
__global__ __launch_bounds__(256, 2) void out_kernel(
    const float* __restrict__ x_agg, const float* __restrict__ ow,
    const float* __restrict__ ob, const float* __restrict__ vdot,
    const float* __restrict__ vec3, const float* __restrict__ vec_agg,
    float* __restrict__ dx, float* __restrict__ dvec) {
  __shared__ float xs[16][128];
  const int t = threadIdx.x;
  const int ch = t & 127, g = t >> 7;
  const int node0 = blockIdx.x * 16;

  for (int idx = t; idx < 16 * 128; idx += 256) {
    int n = idx >> 7, c = idx & 127;
    xs[n][c] = x_agg[(size_t)(node0 + n) * 128 + c];
  }
  __syncthreads();

  float a1[8] = {0, 0, 0, 0, 0, 0, 0, 0};
  float a2[8] = {0, 0, 0, 0, 0, 0, 0, 0};
  float a3[8] = {0, 0, 0, 0, 0, 0, 0, 0};
  gemm8x3<128>(ow + ch, ow + 128 + ch, ow + 256 + ch, 384, &xs[0][0], 128,
               g * 8, a1, a2, a3);
  float b1v = ob[ch], b2v = ob[128 + ch], b3v = ob[256 + ch];
#pragma unroll
  for (int n = 0; n < 8; n++) {
    int node = node0 + g * 8 + n;
    float o1 = a1[n] + b1v, o2 = a2[n] + b2v, o3 = a3[n] + b3v;
    dx[(size_t)node * 128 + ch] = vdot[(size_t)node * 128 + ch] * o2 + o3;
#pragma unroll
    for (int c = 0; c < 3; c++) {
      size_t off = (size_t)node * 384 + c * 128 + ch;
      dvec[off] = vec3[off] * o1 + vec_agg[off];
    }
  }
}

extern "C" void kernel_launch(void* const* d_in, const int* in_sizes, int n_in,
                              void* d_out, int out_size, void* d_ws,
                              size_t ws_size, hipStream_t stream) {
  const float* x = (const float*)d_in[0];
  const float* vec = (const float*)d_in[1];
  const float* na = (const float*)d_in[2];
  const int* ei = (const int*)d_in[3];
  const float* r_ij = (const float*)d_in[4];
  const float* f_ij = (const float*)d_in[5];
  const float* d_ijp = (const float*)d_in[6];
  const float* w1 = (const float*)d_in[7];
  const float* b1 = (const float*)d_in[8];
  const float* w2 = (const float*)d_in[9];
  const float* b2 = (const float*)d_in[10];
  const float* lng = (const float*)d_in[11];
  const float* lnb = (const float*)d_in[12];
  const float* qw = (const float*)d_in[13];
  const float* qb = (const float*)d_in[14];
  const float* kw = (const float*)d_in[15];
  const float* kb = (const float*)d_in[16];
  const float* vw = (const float*)d_in[17];
  const float* vb = (const float*)d_in[18];
  const float* ow = (const float*)d_in[19];
  const float* ob = (const float*)d_in[20];
  const float* vecw = (const float*)d_in[21];
  const float* dkw = (const float*)d_in[22];
  const float* dkb = (const float*)d_in[23];
  const float* dvw = (const float*)d_in[24];
  const float* dvb = (const float*)d_in[25];

  float* ws = (float*)d_ws;
  const size_t NH = (size_t)N_NODES * 128;
  const size_t NH3 = (size_t)N_NODES * 384;
  float* q_o = ws;                 // N*H
  float* k_o = q_o + NH;           // N*H
  float* v_o = k_o + NH;           // N*3H
  float* vdot_o = v_o + NH3;       // N*H
  float* vec3_o = vdot_o + NH;     // N*3H
  float* x_agg = vec3_o + NH3;     // N*H
  float* vec_agg = x_agg + NH;     // N*3H
  unsigned short* wfragE = (unsigned short*)(vec_agg + NH3);  // 32768 ushort
  float* bias512 = (float*)(wfragE + 32768);                  // 512 f32
  unsigned short* wfragN = (unsigned short*)(bias512 + 512);  // 180224 ushort
  int* ibuf = (int*)(wfragN + NWF_TOTAL);
  int* counts = ibuf;              // N
  int* cursor = counts + N_NODES;  // N
  int* total = cursor + N_NODES;   // 1
  int* offsets = total + 1;        // N
  int* perm = offsets + N_NODES;   // E

  hipMemsetAsync(x_agg, 0, (NH + NH3) * sizeof(float), stream);
  hipMemsetAsync(counts, 0, (2 * N_NODES + 1) * sizeof(int), stream);

  wcvt_kernel<<<128, 256, 0, stream>>>(dkw, dkb, dvw, dvb, wfragE, bias512);
  wcvt_node_kernel<<<(NWF_TOTAL + 255) / 256, 256, 0, stream>>>(
      w1, w2, qw, kw, vw, vecw, wfragN);

  node_kernel<<<N_NODES / 16, 256, 0, stream>>>(
      x, vec, na, wfragN, b1, b2, lng, lnb, qb, kb, vb, q_o, k_o, v_o, vdot_o,
      vec3_o);

  hist_kernel<<<(N_EDGES + 255) / 256, 256, 0, stream>>>(ei, counts);
  assign_kernel<<<(N_NODES + 255) / 256, 256, 0, stream>>>(counts, total,
                                                           offsets);
  scatter_kernel<<<(N_EDGES + 255) / 256, 256, 0, stream>>>(ei, offsets, cursor,
                                                            perm);

  edge_kernel<<<N_EDGES / TILE, 256, 0, stream>>>(
      ei, perm, r_ij, f_ij, d_ijp, wfragE, bias512, q_o, k_o, v_o, vec, x_agg,
      vec_agg);

  float* dx = (float*)d_out;
  float* dvec = dx + NH;
  out_kernel<<<N_NODES / 16, 256, 0, stream>>>(x_agg, ow, ob, vdot_o, vec3_o,
                                               vec_agg, dx, dvec);
}

// Round 7
// 447.108 us; speedup vs baseline: 2.3772x; 1.0244x over previous
//
#include <hip/hip_runtime.h>
#include <hip/hip_bf16.h>

#define N_NODES 20000
#define N_EDGES 200000
#define TILE 16
// H = 128, 3H = 384, RBF = 64, HEADS = 8, HD = 16

typedef __attribute__((ext_vector_type(8))) short short8;
typedef __attribute__((ext_vector_type(4))) float f32x4;

__device__ __forceinline__ float silu_f(float x) { return x / (1.f + __expf(-x)); }

__device__ __forceinline__ unsigned short f2bf(float x) {
  __hip_bfloat16 h = __float2bfloat16(x);
  return *(unsigned short*)&h;
}
__device__ __forceinline__ float bf2f(unsigned short u) {
  __hip_bfloat16 h;
  *(unsigned short*)&h = u;
  return __bfloat162float(h);
}
__device__ __forceinline__ unsigned pk2(float a, float b) {
  return (unsigned)f2bf(a) | ((unsigned)f2bf(b) << 16);
}

// node-weight fragment base offsets (ushort units)
#define W1F 0
#define W2F 32768
#define QF 49152
#define KF 65536
#define VF 81920
#define VECF 131072
#define NWF_TOTAL 180224

// ---- f32 register-tiled helper (still used by out_kernel) ----
template <int KDIM>
__device__ __forceinline__ void gemm8x3(const float* __restrict__ wA,
                                        const float* __restrict__ wB,
                                        const float* __restrict__ wC, int wstride,
                                        const float* src, int srcstride, int row0,
                                        float a1[8], float a2[8], float a3[8]) {
  for (int k = 0; k < KDIM; k += 4) {
    float uA0 = wA[(k + 0) * wstride], uA1 = wA[(k + 1) * wstride];
    float uA2 = wA[(k + 2) * wstride], uA3 = wA[(k + 3) * wstride];
    float uB0 = wB[(k + 0) * wstride], uB1 = wB[(k + 1) * wstride];
    float uB2 = wB[(k + 2) * wstride], uB3 = wB[(k + 3) * wstride];
    float uC0 = wC[(k + 0) * wstride], uC1 = wC[(k + 1) * wstride];
    float uC2 = wC[(k + 2) * wstride], uC3 = wC[(k + 3) * wstride];
#pragma unroll
    for (int n = 0; n < 8; n++) {
      const float4 a = *(const float4*)(src + (row0 + n) * srcstride + k);
      a1[n] = fmaf(a.x, uA0, a1[n]); a1[n] = fmaf(a.y, uA1, a1[n]);
      a1[n] = fmaf(a.z, uA2, a1[n]); a1[n] = fmaf(a.w, uA3, a1[n]);
      a2[n] = fmaf(a.x, uB0, a2[n]); a2[n] = fmaf(a.y, uB1, a2[n]);
      a2[n] = fmaf(a.z, uB2, a2[n]); a2[n] = fmaf(a.w, uB3, a2[n]);
      a3[n] = fmaf(a.x, uC0, a3[n]); a3[n] = fmaf(a.y, uC1, a3[n]);
      a3[n] = fmaf(a.z, uC2, a3[n]); a3[n] = fmaf(a.w, uC3, a3[n]);
    }
  }
}

// ========== edge-weight pre-convert: f32 dkw/dvw -> bf16 MFMA B-fragments ====
__global__ void wcvt_kernel(const float* __restrict__ dkw,
                            const float* __restrict__ dkb,
                            const float* __restrict__ dvw,
                            const float* __restrict__ dvb,
                            unsigned short* __restrict__ wfrag,
                            float* __restrict__ bias512) {
  int gid = blockIdx.x * 256 + threadIdx.x;
  if (gid < 32768) {
    int i = gid & 7;
    int l = (gid >> 3) & 63;
    int ks = (gid >> 9) & 1;
    int ct = gid >> 10;
    int k = ks * 32 + ((l >> 4) * 8) + i;
    int col = ct * 16 + (l & 15);
    float v = (col < 128) ? dkw[k * 128 + col] : dvw[k * 384 + (col - 128)];
    wfrag[gid] = f2bf(v);
  }
  if (gid < 512)
    bias512[gid] = (gid < 128) ? dkb[gid] : dvb[gid - 128];
}

// ========== node-weight pre-convert: 6 matrices -> bf16 B-fragments ==========
__global__ void wcvt_node_kernel(const float* __restrict__ w1,
                                 const float* __restrict__ w2,
                                 const float* __restrict__ qw,
                                 const float* __restrict__ kw,
                                 const float* __restrict__ vw,
                                 const float* __restrict__ vecw,
                                 unsigned short* __restrict__ wf) {
  int gid = blockIdx.x * 256 + threadIdx.x;
  if (gid >= NWF_TOTAL) return;
  const float* W;
  int N, KT, loc;
  if (gid < 32768) { W = w1; N = 128; KT = 8; loc = gid; }
  else if (gid < 49152) { W = w2; N = 128; KT = 4; loc = gid - 32768; }
  else if (gid < 65536) { W = qw; N = 128; KT = 4; loc = gid - 49152; }
  else if (gid < 81920) { W = kw; N = 128; KT = 4; loc = gid - 65536; }
  else if (gid < 131072) { W = vw; N = 384; KT = 4; loc = gid - 81920; }
  else { W = vecw; N = 384; KT = 4; loc = gid - 131072; }
  int i = loc & 7, lane = (loc >> 3) & 63, t9 = loc >> 9;
  int kt = t9 % KT, nt = t9 / KT;
  int k = kt * 32 + ((lane >> 4) * 8) + i;
  int n = nt * 16 + (lane & 15);
  wf[gid] = f2bf(W[(size_t)k * N + n]);
}

// ========== vec f32 -> bf16 copy (for edge-kernel gathers) ==========
__global__ void veccvt_kernel(const float* __restrict__ vec,
                              unsigned short* __restrict__ vbf) {
  int gid = blockIdx.x * 256 + threadIdx.x;
  if (gid < N_NODES * 384 / 8) {
    const float4* s = (const float4*)(vec + gid * 8);
    float4 a = s[0], b = s[1];
    uint4 p;
    p.x = pk2(a.x, a.y); p.y = pk2(a.z, a.w);
    p.z = pk2(b.x, b.y); p.w = pk2(b.z, b.w);
    ((uint4*)vbf)[gid] = p;
  }
}

// ================= CSR build: histogram -> parallel offsets -> scatter =======
__global__ void hist_kernel(const int* __restrict__ ei, int* __restrict__ counts) {
  int e = blockIdx.x * 256 + threadIdx.x;
  if (e < N_EDGES) atomicAdd(&counts[ei[N_EDGES + e]], 1);
}

__global__ void assign_kernel(const int* __restrict__ counts,
                              int* __restrict__ total, int* __restrict__ offsets) {
  int n = blockIdx.x * 256 + threadIdx.x;
  if (n < N_NODES) offsets[n] = atomicAdd(total, counts[n]);
}

__global__ void scatter_kernel(const int* __restrict__ ei,
                               const int* __restrict__ offsets,
                               int* __restrict__ cursor, int* __restrict__ perm) {
  int e = blockIdx.x * 256 + threadIdx.x;
  if (e < N_EDGES) {
    int i = ei[N_EDGES + e];
    int slot = atomicAdd(&cursor[i], 1);
    perm[offsets[i] + slot] = e;
  }
}

// ============ Phase A: MFMA node MLP + LN + QKV + vec einsum =================
__global__ __launch_bounds__(256, 4) void node_kernel(
    const float* __restrict__ x, const float* __restrict__ vec,
    const float* __restrict__ na, const unsigned short* __restrict__ wf,
    const float* __restrict__ b1, const float* __restrict__ b2,
    const float* __restrict__ lng, const float* __restrict__ lnb,
    const float* __restrict__ qb, const float* __restrict__ kb,
    const float* __restrict__ vb, unsigned short* __restrict__ q_o,
    unsigned short* __restrict__ k_o, unsigned short* __restrict__ v_o,
    float* __restrict__ vdot_o, float* __restrict__ vec3_o) {
  __shared__ unsigned short in_s[16][264];
  __shared__ unsigned short vec_s[3][16][136];
  __shared__ float hf_s[16][132];
  __shared__ unsigned short h1_s[16][136];
  __shared__ unsigned short h_s[16][136];

  const int t = threadIdx.x;
  const int lane = t & 63, w = t >> 6;
  const int node0 = blockIdx.x * 16;
  const int srow = t & 15, scg = t >> 4;
  const int arow = lane & 15, acol = (lane >> 4) * 8;
  const int drow0 = (lane >> 4) * 4;

  {
    const float* src = (scg < 8) ? &x[(size_t)(node0 + srow) * 128 + scg * 16]
                                 : &na[(size_t)(node0 + srow) * 128 + (scg - 8) * 16];
    float4 v0 = ((const float4*)src)[0], v1 = ((const float4*)src)[1];
    float4 v2 = ((const float4*)src)[2], v3 = ((const float4*)src)[3];
    uint4 p0, p1;
    p0.x = pk2(v0.x, v0.y); p0.y = pk2(v0.z, v0.w);
    p0.z = pk2(v1.x, v1.y); p0.w = pk2(v1.z, v1.w);
    p1.x = pk2(v2.x, v2.y); p1.y = pk2(v2.z, v2.w);
    p1.z = pk2(v3.x, v3.y); p1.w = pk2(v3.z, v3.w);
    *(uint4*)&in_s[srow][scg * 16] = p0;
    *(uint4*)&in_s[srow][scg * 16 + 8] = p1;
  }
#pragma unroll
  for (int ch = 0; ch < 3; ch++) {
    const float* src = &vec[(size_t)(node0 + srow) * 384 + ch * 128 + scg * 8];
    float4 v0 = ((const float4*)src)[0], v1 = ((const float4*)src)[1];
    uint4 p;
    p.x = pk2(v0.x, v0.y); p.y = pk2(v0.z, v0.w);
    p.z = pk2(v1.x, v1.y); p.w = pk2(v1.z, v1.w);
    *(uint4*)&vec_s[ch][srow][scg * 8] = p;
  }
  __syncthreads();

  // ---- mix GEMM1 ----
  {
    short8 af[8];
#pragma unroll
    for (int kt = 0; kt < 8; kt++)
      af[kt] = *(const short8*)&in_s[arow][kt * 32 + acol];
#pragma unroll
    for (int nn = 0; nn < 2; nn++) {
      int nt = w * 2 + nn;
      f32x4 acc = {0.f, 0.f, 0.f, 0.f};
#pragma unroll
      for (int kt = 0; kt < 8; kt++)
        acc = __builtin_amdgcn_mfma_f32_16x16x32_bf16(
            af[kt], *(const short8*)(wf + W1F + ((size_t)(nt * 8 + kt) * 64 + lane) * 8),
            acc, 0, 0, 0);
      int col = nt * 16 + (lane & 15);
      float bb = b1[col];
#pragma unroll
      for (int r = 0; r < 4; r++)
        h1_s[drow0 + r][col] = f2bf(silu_f(acc[r] + bb));
    }
  }
  __syncthreads();

  // ---- mix GEMM2 ----
  {
    short8 ah1[4];
#pragma unroll
    for (int kt = 0; kt < 4; kt++)
      ah1[kt] = *(const short8*)&h1_s[arow][kt * 32 + acol];
#pragma unroll
    for (int nn = 0; nn < 2; nn++) {
      int nt = w * 2 + nn;
      f32x4 acc = {0.f, 0.f, 0.f, 0.f};
#pragma unroll
      for (int kt = 0; kt < 4; kt++)
        acc = __builtin_amdgcn_mfma_f32_16x16x32_bf16(
            ah1[kt], *(const short8*)(wf + W2F + ((size_t)(nt * 4 + kt) * 64 + lane) * 8),
            acc, 0, 0, 0);
      int col = nt * 16 + (lane & 15);
      float bb = b2[col];
#pragma unroll
      for (int r = 0; r < 4; r++) hf_s[drow0 + r][col] = acc[r] + bb;
    }
  }
  __syncthreads();

  // ---- LayerNorm ----
  {
    float lg0 = lng[lane], lg1 = lng[64 + lane];
    float lb0 = lnb[lane], lb1 = lnb[64 + lane];
    for (int nn = w * 4; nn < w * 4 + 4; nn++) {
      float v0 = hf_s[nn][lane], v1 = hf_s[nn][64 + lane];
      float s = v0 + v1, ss = v0 * v0 + v1 * v1;
#pragma unroll
      for (int m = 1; m < 64; m <<= 1) {
        s += __shfl_xor(s, m);
        ss += __shfl_xor(ss, m);
      }
      float mean = s * (1.f / 128.f);
      float var = ss * (1.f / 128.f) - mean * mean;
      float rs = rsqrtf(var + 1e-5f);
      h_s[nn][lane] = f2bf((v0 - mean) * rs * lg0 + lb0);
      h_s[nn][64 + lane] = f2bf((v1 - mean) * rs * lg1 + lb1);
    }
  }
  __syncthreads();

  // ---- q/k/v projections (bf16 outputs) ----
  {
    short8 ah[4];
#pragma unroll
    for (int kt = 0; kt < 4; kt++)
      ah[kt] = *(const short8*)&h_s[arow][kt * 32 + acol];
    for (int u = 0; u < 10; u++) {
      int idx = w * 10 + u;
      int nt, base, ost;
      const float* bias;
      unsigned short* outp;
      if (idx < 8) { nt = idx; base = QF; bias = qb; outp = q_o; ost = 128; }
      else if (idx < 16) { nt = idx - 8; base = KF; bias = kb; outp = k_o; ost = 128; }
      else { nt = idx - 16; base = VF; bias = vb; outp = v_o; ost = 384; }
      f32x4 acc = {0.f, 0.f, 0.f, 0.f};
#pragma unroll
      for (int kt = 0; kt < 4; kt++)
        acc = __builtin_amdgcn_mfma_f32_16x16x32_bf16(
            ah[kt], *(const short8*)(wf + base + ((size_t)(nt * 4 + kt) * 64 + lane) * 8),
            acc, 0, 0, 0);
      int col = nt * 16 + (lane & 15);
      float bv = bias[col];
#pragma unroll
      for (int r = 0; r < 4; r++)
        outp[(node0 + drow0 + r) * ost + col] = f2bf(acc[r] + bv);
    }
  }

  // ---- vec einsum ----
  {
    f32x4 vd0 = {0.f, 0.f, 0.f, 0.f}, vd1 = {0.f, 0.f, 0.f, 0.f};
#pragma unroll
    for (int ch = 0; ch < 3; ch++) {
      short8 av[4];
#pragma unroll
      for (int kt = 0; kt < 4; kt++)
        av[kt] = *(const short8*)&vec_s[ch][arow][kt * 32 + acol];
#pragma unroll
      for (int nn = 0; nn < 2; nn++) {
        int nt1 = w * 2 + nn, nt2 = 8 + w * 2 + nn, nt3 = 16 + w * 2 + nn;
        f32x4 p1 = {0.f, 0.f, 0.f, 0.f}, p2 = {0.f, 0.f, 0.f, 0.f},
              p3 = {0.f, 0.f, 0.f, 0.f};
#pragma unroll
        for (int kt = 0; kt < 4; kt++) {
          p1 = __builtin_amdgcn_mfma_f32_16x16x32_bf16(
              av[kt], *(const short8*)(wf + VECF + ((size_t)(nt1 * 4 + kt) * 64 + lane) * 8),
              p1, 0, 0, 0);
          p2 = __builtin_amdgcn_mfma_f32_16x16x32_bf16(
              av[kt], *(const short8*)(wf + VECF + ((size_t)(nt2 * 4 + kt) * 64 + lane) * 8),
              p2, 0, 0, 0);
          p3 = __builtin_amdgcn_mfma_f32_16x16x32_bf16(
              av[kt], *(const short8*)(wf + VECF + ((size_t)(nt3 * 4 + kt) * 64 + lane) * 8),
              p3, 0, 0, 0);
        }
        if (nn == 0) vd0 += p1 * p2; else vd1 += p1 * p2;
        int col = (w * 2 + nn) * 16 + (lane & 15);
#pragma unroll
        for (int r = 0; r < 4; r++)
          vec3_o[(size_t)(node0 + drow0 + r) * 384 + ch * 128 + col] = p3[r];
      }
    }
#pragma unroll
    for (int nn = 0; nn < 2; nn++) {
      int col = (w * 2 + nn) * 16 + (lane & 15);
      f32x4 vd = (nn == 0) ? vd0 : vd1;
#pragma unroll
      for (int r = 0; r < 4; r++)
        vdot_o[(size_t)(node0 + drow0 + r) * 128 + col] = vd[r];
    }
  }
}

// ====== Phase B: MFMA dkv GEMM + attention + run-accumulated scatter =========
__global__ __launch_bounds__(256, 6) void edge_kernel(
    const int* __restrict__ ei, const int* __restrict__ perm,
    const float* __restrict__ r_ij, const float* __restrict__ f_ij,
    const float* __restrict__ d_ij, const unsigned short* __restrict__ wfrag,
    const float* __restrict__ bias512, const unsigned short* __restrict__ q_ws,
    const unsigned short* __restrict__ k_ws,
    const unsigned short* __restrict__ v_ws,
    const unsigned short* __restrict__ vec_bf, float* __restrict__ x_agg,
    float* __restrict__ vec_agg) {
  __shared__ unsigned short f_s[TILE][72];
  __shared__ unsigned short dkv_s[TILE][520];
  __shared__ int j_s[TILE];
  __shared__ int i_s[TILE];
  __shared__ float cut_s[TILE];
  __shared__ float d_s[TILE][3];

  const int t = threadIdx.x;
  const int e0 = blockIdx.x * TILE;

  if (t < TILE) {
    int e = perm[e0 + t];
    j_s[t] = ei[e];
    i_s[t] = ei[N_EDGES + e];
    float r = r_ij[e];
    cut_s[t] = 0.5f * (__cosf(r * 0.31415926535f) + 1.f) * (r < 10.f ? 1.f : 0.f);
    d_s[t][0] = d_ij[e * 3 + 0];
    d_s[t][1] = d_ij[e * 3 + 1];
    d_s[t][2] = d_ij[e * 3 + 2];
  }
  if (t < 128) {
    int row = t >> 3, c0 = (t & 7) * 8;
    int e = perm[e0 + row];
    const float4* src = (const float4*)&f_ij[(size_t)e * 64 + c0];
    float4 v0 = src[0], v1 = src[1];
    uint4 pk;
    pk.x = pk2(v0.x, v0.y);
    pk.y = pk2(v0.z, v0.w);
    pk.z = pk2(v1.x, v1.y);
    pk.w = pk2(v1.z, v1.w);
    *(uint4*)&f_s[row][c0] = pk;
  }
  __syncthreads();

  {
    const int lane = t & 63, wave = t >> 6;
    const unsigned short* arow = &f_s[lane & 15][(lane >> 4) * 8];
    short8 a0 = *(const short8*)arow;
    short8 a1 = *(const short8*)(arow + 32);
#pragma unroll
    for (int c = 0; c < 8; c++) {
      int ct = wave * 8 + c;
      short8 b0 = *(const short8*)(wfrag + ((size_t)(ct * 2 + 0) * 64 + lane) * 8);
      short8 b1 = *(const short8*)(wfrag + ((size_t)(ct * 2 + 1) * 64 + lane) * 8);
      f32x4 acc = {0.f, 0.f, 0.f, 0.f};
      acc = __builtin_amdgcn_mfma_f32_16x16x32_bf16(a0, b0, acc, 0, 0, 0);
      acc = __builtin_amdgcn_mfma_f32_16x16x32_bf16(a1, b1, acc, 0, 0, 0);
      int col = ct * 16 + (lane & 15);
      float bb = bias512[col];
#pragma unroll
      for (int r = 0; r < 4; r++) {
        int eg = (lane >> 4) * 4 + r;
        dkv_s[eg][col] = f2bf(silu_f(acc[r] + bb));
      }
    }
  }
  __syncthreads();

  {
    const int ch = t & 127, g2 = t >> 7;
    const int h = ch >> 4, d = ch & 15;
    const int vcol = h * 48 + d;
    const int ee0 = g2 * 8, ee1 = ee0 + 8;

    float rx = 0.f, rv0 = 0.f, rv1 = 0.f, rv2 = 0.f;
    int cur_i = i_s[ee0];
    float qv = bf2f(q_ws[cur_i * 128 + ch]);

    for (int ee = ee0; ee < ee1; ee++) {
      int i = i_s[ee], j = j_s[ee];
      if (i != cur_i) {
        atomicAdd(&x_agg[cur_i * 128 + ch], rx);
        atomicAdd(&vec_agg[cur_i * 384 + ch], rv0);
        atomicAdd(&vec_agg[cur_i * 384 + 128 + ch], rv1);
        atomicAdd(&vec_agg[cur_i * 384 + 256 + ch], rv2);
        rx = rv0 = rv1 = rv2 = 0.f;
        cur_i = i;
        qv = bf2f(q_ws[i * 128 + ch]);
      }
      float ddk = bf2f(dkv_s[ee][ch]);
      float kv = bf2f(k_ws[j * 128 + ch]);
      float p = qv * kv * ddk;
      p += __shfl_xor(p, 1);
      p += __shfl_xor(p, 2);
      p += __shfl_xor(p, 4);
      p += __shfl_xor(p, 8);
      float a = silu_f(p) * cut_s[ee];
      float dv0 = bf2f(dkv_s[ee][128 + vcol]);
      float dv1 = bf2f(dkv_s[ee][128 + vcol + 16]);
      float dv2 = bf2f(dkv_s[ee][128 + vcol + 32]);
      const unsigned short* vr = &v_ws[j * 384];
      float v0 = bf2f(vr[vcol]), v1 = bf2f(vr[vcol + 16]), v2 = bf2f(vr[vcol + 32]);
      rx += v0 * dv0 * a;
      float v1m = v1 * dv1, v2m = v2 * dv2;
      const unsigned short* vj = &vec_bf[j * 384];
      rv0 += bf2f(vj[ch]) * v1m + v2m * d_s[ee][0];
      rv1 += bf2f(vj[128 + ch]) * v1m + v2m * d_s[ee][1];
      rv2 += bf2f(vj[256 + ch]) * v1m + v2m * d_s[ee][2];
    }
    atomicAdd(&x_agg[cur_i * 128 + ch], rx);
    atomicAdd(&vec_agg[cur_i * 384 + ch], rv0);
    atomicAdd(&vec_agg[cur_i * 384 + 128 + ch], rv1);
    atomicAdd(&vec_agg[cur_i * 384 + 256 + ch], rv2);
  }
}

// ================= Phase C: output projection + epilogue =====================
__global__ __launch_bounds__(256, 2) void out_kernel(
    const float* __restrict__ x_agg, const float* __restrict__ ow,
    const float* __restrict__ ob, const float* __restrict__ vdot,
    const float* __restrict__ vec3, const float* __restrict__ vec_agg,
    float* __restrict__ dx, float* __restrict__ dvec) {
  __shared__ float xs[16][128];
  const int t = threadIdx.x;
  const int ch = t & 127, g = t >> 7;
  const int node0 = blockIdx.x * 16;

  for (int idx = t; idx < 16 * 128; idx += 256) {
    int n = idx >> 7, c = idx & 127;
    xs[n][c] = x_agg[(size_t)(node0 + n) * 128 + c];
  }
  __syncthreads();

  float a1[8] = {0, 0, 0, 0, 0, 0, 0, 0};
  float a2[8] = {0, 0, 0, 0, 0, 0, 0, 0};
  float a3[8] = {0, 0, 0, 0, 0, 0, 0, 0};
  gemm8x3<128>(ow + ch, ow + 128 + ch, ow + 256 + ch, 384, &xs[0][0], 128,
               g * 8, a1, a2, a3);
  float b1v = ob[ch], b2v = ob[128 + ch], b3v = ob[256 + ch];
#pragma unroll
  for (int n = 0; n < 8; n++) {
    int node = node0 + g * 8 + n;
    float o1 = a1[n] + b1v, o2 = a2[n] + b2v, o3 = a3[n] + b3v;
    dx[(size_t)node * 128 + ch] = vdot[(size_t)node * 128 + ch] * o2 + o3;
#pragma unroll
    for (int c = 0; c < 3; c++) {
      size_t off = (size_t)node * 384 + c * 128 + ch;
      dvec[off] = vec3[off] * o1 + vec_agg[off];
    }
  }
}

extern "C" void kernel_launch(void* const* d_in, const int* in_sizes, int n_in,
                              void* d_out, int out_size, void* d_ws,
                              size_t ws_size, hipStream_t stream) {
  const float* x = (const float*)d_in[0];
  const float* vec = (const float*)d_in[1];
  const float* na = (const float*)d_in[2];
  const int* ei = (const int*)d_in[3];
  const float* r_ij = (const float*)d_in[4];
  const float* f_ij = (const float*)d_in[5];
  const float* d_ijp = (const float*)d_in[6];
  const float* w1 = (const float*)d_in[7];
  const float* b1 = (const float*)d_in[8];
  const float* w2 = (const float*)d_in[9];
  const float* b2 = (const float*)d_in[10];
  const float* lng = (const float*)d_in[11];
  const float* lnb = (const float*)d_in[12];
  const float* qw = (const float*)d_in[13];
  const float* qb = (const float*)d_in[14];
  const float* kw = (const float*)d_in[15];
  const float* kb = (const float*)d_in[16];
  const float* vw = (const float*)d_in[17];
  const float* vb = (const float*)d_in[18];
  const float* ow = (const float*)d_in[19];
  const float* ob = (const float*)d_in[20];
  const float* vecw = (const float*)d_in[21];
  const float* dkw = (const float*)d_in[22];
  const float* dkb = (const float*)d_in[23];
  const float* dvw = (const float*)d_in[24];
  const float* dvb = (const float*)d_in[25];

  float* ws = (float*)d_ws;
  const size_t NH = (size_t)N_NODES * 128;
  const size_t NH3 = (size_t)N_NODES * 384;
  float* vdot_o = ws;              // N*H f32
  float* vec3_o = vdot_o + NH;     // N*3H f32
  float* x_agg = vec3_o + NH3;     // N*H f32
  float* vec_agg = x_agg + NH;     // N*3H f32
  unsigned short* q_bf = (unsigned short*)(vec_agg + NH3);  // N*H
  unsigned short* k_bf = q_bf + NH;                         // N*H
  unsigned short* v_bf = k_bf + NH;                         // N*3H
  unsigned short* vec_bf = v_bf + NH3;                      // N*3H
  unsigned short* wfragE = vec_bf + NH3;                    // 32768
  float* bias512 = (float*)(wfragE + 32768);                // 512 f32
  unsigned short* wfragN = (unsigned short*)(bias512 + 512);
  int* ibuf = (int*)(wfragN + NWF_TOTAL);
  int* counts = ibuf;              // N
  int* cursor = counts + N_NODES;  // N
  int* total = cursor + N_NODES;   // 1
  int* offsets = total + 1;        // N
  int* perm = offsets + N_NODES;   // E

  hipMemsetAsync(x_agg, 0, (NH + NH3) * sizeof(float), stream);
  hipMemsetAsync(counts, 0, (2 * N_NODES + 1) * sizeof(int), stream);

  wcvt_kernel<<<128, 256, 0, stream>>>(dkw, dkb, dvw, dvb, wfragE, bias512);
  wcvt_node_kernel<<<(NWF_TOTAL + 255) / 256, 256, 0, stream>>>(
      w1, w2, qw, kw, vw, vecw, wfragN);
  veccvt_kernel<<<(N_NODES * 384 / 8 + 255) / 256, 256, 0, stream>>>(vec,
                                                                     vec_bf);

  node_kernel<<<N_NODES / 16, 256, 0, stream>>>(
      x, vec, na, wfragN, b1, b2, lng, lnb, qb, kb, vb, q_bf, k_bf, v_bf,
      vdot_o, vec3_o);

  hist_kernel<<<(N_EDGES + 255) / 256, 256, 0, stream>>>(ei, counts);
  assign_kernel<<<(N_NODES + 255) / 256, 256, 0, stream>>>(counts, total,
                                                           offsets);
  scatter_kernel<<<(N_EDGES + 255) / 256, 256, 0, stream>>>(ei, offsets, cursor,
                                                            perm);

  edge_kernel<<<N_EDGES / TILE, 256, 0, stream>>>(
      ei, perm, r_ij, f_ij, d_ijp, wfragE, bias512, q_bf, k_bf, v_bf, vec_bf,
      x_agg, vec_agg);

  float* dx = (float*)d_out;
  float* dvec = dx + NH;
  out_kernel<<<N_NODES / 16, 256, 0, stream>>>(x_agg, ow, ob, vdot_o, vec3_o,
                                               vec_agg, dx, dvec);
}

// Round 10
// 438.057 us; speedup vs baseline: 2.4263x; 1.0207x over previous
//
#include <hip/hip_runtime.h>
#include <hip/hip_bf16.h>

#define N_NODES 20000
#define N_EDGES 200000
#define TILE 16
// H = 128, 3H = 384, RBF = 64, HEADS = 8, HD = 16

typedef __attribute__((ext_vector_type(8))) short short8;
typedef __attribute__((ext_vector_type(4))) float f32x4;

__device__ __forceinline__ float silu_f(float x) { return x / (1.f + __expf(-x)); }

__device__ __forceinline__ unsigned short f2bf(float x) {
  __hip_bfloat16 h = __float2bfloat16(x);
  return *(unsigned short*)&h;
}
__device__ __forceinline__ float bf2f(unsigned short u) {
  __hip_bfloat16 h;
  *(unsigned short*)&h = u;
  return __bfloat162float(h);
}
__device__ __forceinline__ unsigned pk2(float a, float b) {
  return (unsigned)f2bf(a) | ((unsigned)f2bf(b) << 16);
}

// node-weight fragment base offsets (ushort units)
#define W1F 0
#define W2F 32768
#define QF 49152
#define KF 65536
#define VF 81920
#define VECF 131072
#define NWF_TOTAL 180224

// fused-prep gid ranges
#define PREP_A 32768                 // edge wfrag
#define PREP_B (PREP_A + 512)        // bias512
#define PREP_C (PREP_B + NWF_TOTAL)  // node wfrag
#define PREP_D (PREP_C + 960000)     // veccvt (N*384/8)

// ---- f32 register-tiled helper (out_kernel: o-projection must stay f32 —
// bf16 staging of x_agg failed absmax in round 8) ----
template <int KDIM>
__device__ __forceinline__ void gemm8x3(const float* __restrict__ wA,
                                        const float* __restrict__ wB,
                                        const float* __restrict__ wC, int wstride,
                                        const float* src, int srcstride, int row0,
                                        float a1[8], float a2[8], float a3[8]) {
  for (int k = 0; k < KDIM; k += 4) {
    float uA0 = wA[(k + 0) * wstride], uA1 = wA[(k + 1) * wstride];
    float uA2 = wA[(k + 2) * wstride], uA3 = wA[(k + 3) * wstride];
    float uB0 = wB[(k + 0) * wstride], uB1 = wB[(k + 1) * wstride];
    float uB2 = wB[(k + 2) * wstride], uB3 = wB[(k + 3) * wstride];
    float uC0 = wC[(k + 0) * wstride], uC1 = wC[(k + 1) * wstride];
    float uC2 = wC[(k + 2) * wstride], uC3 = wC[(k + 3) * wstride];
#pragma unroll
    for (int n = 0; n < 8; n++) {
      const float4 a = *(const float4*)(src + (row0 + n) * srcstride + k);
      a1[n] = fmaf(a.x, uA0, a1[n]); a1[n] = fmaf(a.y, uA1, a1[n]);
      a1[n] = fmaf(a.z, uA2, a1[n]); a1[n] = fmaf(a.w, uA3, a1[n]);
      a2[n] = fmaf(a.x, uB0, a2[n]); a2[n] = fmaf(a.y, uB1, a2[n]);
      a2[n] = fmaf(a.z, uB2, a2[n]); a2[n] = fmaf(a.w, uB3, a2[n]);
      a3[n] = fmaf(a.x, uC0, a3[n]); a3[n] = fmaf(a.y, uC1, a3[n]);
      a3[n] = fmaf(a.z, uC2, a3[n]); a3[n] = fmaf(a.w, uC3, a3[n]);
    }
  }
}

// ====== fused prep: edge wfrag + bias + node wfrag + vec->bf16 ==============
__global__ void prep_kernel(const float* __restrict__ dkw,
                            const float* __restrict__ dkb,
                            const float* __restrict__ dvw,
                            const float* __restrict__ dvb,
                            const float* __restrict__ w1,
                            const float* __restrict__ w2,
                            const float* __restrict__ qw,
                            const float* __restrict__ kw,
                            const float* __restrict__ vw,
                            const float* __restrict__ vecw,
                            const float* __restrict__ vec,
                            unsigned short* __restrict__ wfragE,
                            float* __restrict__ bias512,
                            unsigned short* __restrict__ wfragN,
                            unsigned short* __restrict__ vec_bf) {
  int gid = blockIdx.x * 256 + threadIdx.x;
  if (gid < PREP_A) {
    int i = gid & 7;
    int l = (gid >> 3) & 63;
    int ks = (gid >> 9) & 1;
    int ct = gid >> 10;
    int k = ks * 32 + ((l >> 4) * 8) + i;
    int col = ct * 16 + (l & 15);
    float v = (col < 128) ? dkw[k * 128 + col] : dvw[k * 384 + (col - 128)];
    wfragE[gid] = f2bf(v);
  } else if (gid < PREP_B) {
    int b = gid - PREP_A;
    bias512[b] = (b < 128) ? dkb[b] : dvb[b - 128];
  } else if (gid < PREP_C) {
    int loc0 = gid - PREP_B;
    const float* W;
    int N, KT, loc;
    if (loc0 < 32768) { W = w1; N = 128; KT = 8; loc = loc0; }
    else if (loc0 < 49152) { W = w2; N = 128; KT = 4; loc = loc0 - 32768; }
    else if (loc0 < 65536) { W = qw; N = 128; KT = 4; loc = loc0 - 49152; }
    else if (loc0 < 81920) { W = kw; N = 128; KT = 4; loc = loc0 - 65536; }
    else if (loc0 < 131072) { W = vw; N = 384; KT = 4; loc = loc0 - 81920; }
    else { W = vecw; N = 384; KT = 4; loc = loc0 - 131072; }
    int i = loc & 7, lane = (loc >> 3) & 63, t9 = loc >> 9;
    int kt = t9 % KT, nt = t9 / KT;
    int k = kt * 32 + ((lane >> 4) * 8) + i;
    int n = nt * 16 + (lane & 15);
    wfragN[loc0] = f2bf(W[(size_t)k * N + n]);
  } else if (gid < PREP_D) {
    int g = gid - PREP_C;
    const float4* s = (const float4*)(vec + (size_t)g * 8);
    float4 a = s[0], b = s[1];
    uint4 p;
    p.x = pk2(a.x, a.y); p.y = pk2(a.z, a.w);
    p.z = pk2(b.x, b.y); p.w = pk2(b.z, b.w);
    ((uint4*)vec_bf)[g] = p;
  }
}

// ================= CSR build: histogram -> parallel offsets -> scatter =======
__global__ void hist_kernel(const int* __restrict__ ei, int* __restrict__ counts) {
  int e = blockIdx.x * 256 + threadIdx.x;
  if (e < N_EDGES) atomicAdd(&counts[ei[N_EDGES + e]], 1);
}

__global__ void assign_kernel(const int* __restrict__ counts,
                              int* __restrict__ total, int* __restrict__ offsets) {
  int n = blockIdx.x * 256 + threadIdx.x;
  if (n < N_NODES) offsets[n] = atomicAdd(total, counts[n]);
}

__global__ void scatter_kernel(const int* __restrict__ ei,
                               const int* __restrict__ offsets,
                               int* __restrict__ cursor, int* __restrict__ perm) {
  int e = blockIdx.x * 256 + threadIdx.x;
  if (e < N_EDGES) {
    int i = ei[N_EDGES + e];
    int slot = atomicAdd(&cursor[i], 1);
    perm[offsets[i] + slot] = e;
  }
}

// ============ Phase A: MFMA node MLP + LN + QKV + vec einsum =================
__global__ __launch_bounds__(256, 4) void node_kernel(
    const float* __restrict__ x, const float* __restrict__ vec,
    const float* __restrict__ na, const unsigned short* __restrict__ wf,
    const float* __restrict__ b1, const float* __restrict__ b2,
    const float* __restrict__ lng, const float* __restrict__ lnb,
    const float* __restrict__ qb, const float* __restrict__ kb,
    const float* __restrict__ vb, unsigned short* __restrict__ q_o,
    unsigned short* __restrict__ k_o, unsigned short* __restrict__ v_o,
    float* __restrict__ vdot_o, float* __restrict__ vec3_o) {
  __shared__ unsigned short in_s[16][264];
  __shared__ unsigned short vec_s[3][16][136];
  __shared__ float hf_s[16][132];
  __shared__ unsigned short h1_s[16][136];
  __shared__ unsigned short h_s[16][136];

  const int t = threadIdx.x;
  const int lane = t & 63, w = t >> 6;
  const int node0 = blockIdx.x * 16;
  const int srow = t & 15, scg = t >> 4;
  const int arow = lane & 15, acol = (lane >> 4) * 8;
  const int drow0 = (lane >> 4) * 4;

  {
    const float* src = (scg < 8) ? &x[(size_t)(node0 + srow) * 128 + scg * 16]
                                 : &na[(size_t)(node0 + srow) * 128 + (scg - 8) * 16];
    float4 v0 = ((const float4*)src)[0], v1 = ((const float4*)src)[1];
    float4 v2 = ((const float4*)src)[2], v3 = ((const float4*)src)[3];
    uint4 p0, p1;
    p0.x = pk2(v0.x, v0.y); p0.y = pk2(v0.z, v0.w);
    p0.z = pk2(v1.x, v1.y); p0.w = pk2(v1.z, v1.w);
    p1.x = pk2(v2.x, v2.y); p1.y = pk2(v2.z, v2.w);
    p1.z = pk2(v3.x, v3.y); p1.w = pk2(v3.z, v3.w);
    *(uint4*)&in_s[srow][scg * 16] = p0;
    *(uint4*)&in_s[srow][scg * 16 + 8] = p1;
  }
#pragma unroll
  for (int ch = 0; ch < 3; ch++) {
    const float* src = &vec[(size_t)(node0 + srow) * 384 + ch * 128 + scg * 8];
    float4 v0 = ((const float4*)src)[0], v1 = ((const float4*)src)[1];
    uint4 p;
    p.x = pk2(v0.x, v0.y); p.y = pk2(v0.z, v0.w);
    p.z = pk2(v1.x, v1.y); p.w = pk2(v1.z, v1.w);
    *(uint4*)&vec_s[ch][srow][scg * 8] = p;
  }
  __syncthreads();

  // ---- mix GEMM1 ----
  {
    short8 af[8];
#pragma unroll
    for (int kt = 0; kt < 8; kt++)
      af[kt] = *(const short8*)&in_s[arow][kt * 32 + acol];
#pragma unroll
    for (int nn = 0; nn < 2; nn++) {
      int nt = w * 2 + nn;
      f32x4 acc = {0.f, 0.f, 0.f, 0.f};
#pragma unroll
      for (int kt = 0; kt < 8; kt++)
        acc = __builtin_amdgcn_mfma_f32_16x16x32_bf16(
            af[kt], *(const short8*)(wf + W1F + ((size_t)(nt * 8 + kt) * 64 + lane) * 8),
            acc, 0, 0, 0);
      int col = nt * 16 + (lane & 15);
      float bb = b1[col];
#pragma unroll
      for (int r = 0; r < 4; r++)
        h1_s[drow0 + r][col] = f2bf(silu_f(acc[r] + bb));
    }
  }
  __syncthreads();

  // ---- mix GEMM2 ----
  {
    short8 ah1[4];
#pragma unroll
    for (int kt = 0; kt < 4; kt++)
      ah1[kt] = *(const short8*)&h1_s[arow][kt * 32 + acol];
#pragma unroll
    for (int nn = 0; nn < 2; nn++) {
      int nt = w * 2 + nn;
      f32x4 acc = {0.f, 0.f, 0.f, 0.f};
#pragma unroll
      for (int kt = 0; kt < 4; kt++)
        acc = __builtin_amdgcn_mfma_f32_16x16x32_bf16(
            ah1[kt], *(const short8*)(wf + W2F + ((size_t)(nt * 4 + kt) * 64 + lane) * 8),
            acc, 0, 0, 0);
      int col = nt * 16 + (lane & 15);
      float bb = b2[col];
#pragma unroll
      for (int r = 0; r < 4; r++) hf_s[drow0 + r][col] = acc[r] + bb;
    }
  }
  __syncthreads();

  // ---- LayerNorm ----
  {
    float lg0 = lng[lane], lg1 = lng[64 + lane];
    float lb0 = lnb[lane], lb1 = lnb[64 + lane];
    for (int nn = w * 4; nn < w * 4 + 4; nn++) {
      float v0 = hf_s[nn][lane], v1 = hf_s[nn][64 + lane];
      float s = v0 + v1, ss = v0 * v0 + v1 * v1;
#pragma unroll
      for (int m = 1; m < 64; m <<= 1) {
        s += __shfl_xor(s, m);
        ss += __shfl_xor(ss, m);
      }
      float mean = s * (1.f / 128.f);
      float var = ss * (1.f / 128.f) - mean * mean;
      float rs = rsqrtf(var + 1e-5f);
      h_s[nn][lane] = f2bf((v0 - mean) * rs * lg0 + lb0);
      h_s[nn][64 + lane] = f2bf((v1 - mean) * rs * lg1 + lb1);
    }
  }
  __syncthreads();

  // ---- q/k/v projections (bf16 outputs) ----
  {
    short8 ah[4];
#pragma unroll
    for (int kt = 0; kt < 4; kt++)
      ah[kt] = *(const short8*)&h_s[arow][kt * 32 + acol];
    for (int u = 0; u < 10; u++) {
      int idx = w * 10 + u;
      int nt, base, ost;
      const float* bias;
      unsigned short* outp;
      if (idx < 8) { nt = idx; base = QF; bias = qb; outp = q_o; ost = 128; }
      else if (idx < 16) { nt = idx - 8; base = KF; bias = kb; outp = k_o; ost = 128; }
      else { nt = idx - 16; base = VF; bias = vb; outp = v_o; ost = 384; }
      f32x4 acc = {0.f, 0.f, 0.f, 0.f};
#pragma unroll
      for (int kt = 0; kt < 4; kt++)
        acc = __builtin_amdgcn_mfma_f32_16x16x32_bf16(
            ah[kt], *(const short8*)(wf + base + ((size_t)(nt * 4 + kt) * 64 + lane) * 8),
            acc, 0, 0, 0);
      int col = nt * 16 + (lane & 15);
      float bv = bias[col];
#pragma unroll
      for (int r = 0; r < 4; r++)
        outp[(node0 + drow0 + r) * ost + col] = f2bf(acc[r] + bv);
    }
  }

  // ---- vec einsum ----
  {
    f32x4 vd0 = {0.f, 0.f, 0.f, 0.f}, vd1 = {0.f, 0.f, 0.f, 0.f};
#pragma unroll
    for (int ch = 0; ch < 3; ch++) {
      short8 av[4];
#pragma unroll
      for (int kt = 0; kt < 4; kt++)
        av[kt] = *(const short8*)&vec_s[ch][arow][kt * 32 + acol];
#pragma unroll
      for (int nn = 0; nn < 2; nn++) {
        int nt1 = w * 2 + nn, nt2 = 8 + w * 2 + nn, nt3 = 16 + w * 2 + nn;
        f32x4 p1 = {0.f, 0.f, 0.f, 0.f}, p2 = {0.f, 0.f, 0.f, 0.f},
              p3 = {0.f, 0.f, 0.f, 0.f};
#pragma unroll
        for (int kt = 0; kt < 4; kt++) {
          p1 = __builtin_amdgcn_mfma_f32_16x16x32_bf16(
              av[kt], *(const short8*)(wf + VECF + ((size_t)(nt1 * 4 + kt) * 64 + lane) * 8),
              p1, 0, 0, 0);
          p2 = __builtin_amdgcn_mfma_f32_16x16x32_bf16(
              av[kt], *(const short8*)(wf + VECF + ((size_t)(nt2 * 4 + kt) * 64 + lane) * 8),
              p2, 0, 0, 0);
          p3 = __builtin_amdgcn_mfma_f32_16x16x32_bf16(
              av[kt], *(const short8*)(wf + VECF + ((size_t)(nt3 * 4 + kt) * 64 + lane) * 8),
              p3, 0, 0, 0);
        }
        if (nn == 0) vd0 += p1 * p2; else vd1 += p1 * p2;
        int col = (w * 2 + nn) * 16 + (lane & 15);
#pragma unroll
        for (int r = 0; r < 4; r++)
          vec3_o[(size_t)(node0 + drow0 + r) * 384 + ch * 128 + col] = p3[r];
      }
    }
#pragma unroll
    for (int nn = 0; nn < 2; nn++) {
      int col = (w * 2 + nn) * 16 + (lane & 15);
      f32x4 vd = (nn == 0) ? vd0 : vd1;
#pragma unroll
      for (int r = 0; r < 4; r++)
        vdot_o[(size_t)(node0 + drow0 + r) * 128 + col] = vd[r];
    }
  }
}

// ====== Phase B: MFMA dkv GEMM + attention + run-accumulated scatter =========
// (1ch/lane accumulate loop — the round-8/9 2ch repack regressed absmax;
//  suspected type-punned-load miscompile; keep ushort-typed loads)
__global__ __launch_bounds__(256, 8) void edge_kernel(
    const int* __restrict__ ei, const int* __restrict__ perm,
    const float* __restrict__ r_ij, const float* __restrict__ f_ij,
    const float* __restrict__ d_ij, const unsigned short* __restrict__ wfrag,
    const float* __restrict__ bias512, const unsigned short* __restrict__ q_ws,
    const unsigned short* __restrict__ k_ws,
    const unsigned short* __restrict__ v_ws,
    const unsigned short* __restrict__ vec_bf, float* __restrict__ x_agg,
    float* __restrict__ vec_agg) {
  __shared__ unsigned short f_s[TILE][72];
  __shared__ unsigned short dkv_s[TILE][520];
  __shared__ int j_s[TILE];
  __shared__ int i_s[TILE];
  __shared__ float cut_s[TILE];
  __shared__ float d_s[TILE][3];

  const int t = threadIdx.x;
  const int e0 = blockIdx.x * TILE;

  if (t < TILE) {
    int e = perm[e0 + t];
    j_s[t] = ei[e];
    i_s[t] = ei[N_EDGES + e];
    float r = r_ij[e];
    cut_s[t] = 0.5f * (__cosf(r * 0.31415926535f) + 1.f) * (r < 10.f ? 1.f : 0.f);
    d_s[t][0] = d_ij[e * 3 + 0];
    d_s[t][1] = d_ij[e * 3 + 1];
    d_s[t][2] = d_ij[e * 3 + 2];
  }
  if (t < 128) {
    int row = t >> 3, c0 = (t & 7) * 8;
    int e = perm[e0 + row];
    const float4* src = (const float4*)&f_ij[(size_t)e * 64 + c0];
    float4 v0 = src[0], v1 = src[1];
    uint4 pk;
    pk.x = pk2(v0.x, v0.y);
    pk.y = pk2(v0.z, v0.w);
    pk.z = pk2(v1.x, v1.y);
    pk.w = pk2(v1.z, v1.w);
    *(uint4*)&f_s[row][c0] = pk;
  }
  __syncthreads();

  {
    const int lane = t & 63, wave = t >> 6;
    const unsigned short* arow = &f_s[lane & 15][(lane >> 4) * 8];
    short8 a0 = *(const short8*)arow;
    short8 a1 = *(const short8*)(arow + 32);
#pragma unroll
    for (int c = 0; c < 8; c++) {
      int ct = wave * 8 + c;
      short8 b0 = *(const short8*)(wfrag + ((size_t)(ct * 2 + 0) * 64 + lane) * 8);
      short8 b1 = *(const short8*)(wfrag + ((size_t)(ct * 2 + 1) * 64 + lane) * 8);
      f32x4 acc = {0.f, 0.f, 0.f, 0.f};
      acc = __builtin_amdgcn_mfma_f32_16x16x32_bf16(a0, b0, acc, 0, 0, 0);
      acc = __builtin_amdgcn_mfma_f32_16x16x32_bf16(a1, b1, acc, 0, 0, 0);
      int col = ct * 16 + (lane & 15);
      float bb = bias512[col];
#pragma unroll
      for (int r = 0; r < 4; r++) {
        int eg = (lane >> 4) * 4 + r;
        dkv_s[eg][col] = f2bf(silu_f(acc[r] + bb));
      }
    }
  }
  __syncthreads();

  {
    const int ch = t & 127, g2 = t >> 7;
    const int h = ch >> 4, d = ch & 15;
    const int vcol = h * 48 + d;
    const int ee0 = g2 * 8, ee1 = ee0 + 8;

    float rx = 0.f, rv0 = 0.f, rv1 = 0.f, rv2 = 0.f;
    int cur_i = i_s[ee0];
    float qv = bf2f(q_ws[cur_i * 128 + ch]);

    for (int ee = ee0; ee < ee1; ee++) {
      int i = i_s[ee], j = j_s[ee];
      if (i != cur_i) {
        atomicAdd(&x_agg[cur_i * 128 + ch], rx);
        atomicAdd(&vec_agg[cur_i * 384 + ch], rv0);
        atomicAdd(&vec_agg[cur_i * 384 + 128 + ch], rv1);
        atomicAdd(&vec_agg[cur_i * 384 + 256 + ch], rv2);
        rx = rv0 = rv1 = rv2 = 0.f;
        cur_i = i;
        qv = bf2f(q_ws[i * 128 + ch]);
      }
      float ddk = bf2f(dkv_s[ee][ch]);
      float kv = bf2f(k_ws[j * 128 + ch]);
      float p = qv * kv * ddk;
      p += __shfl_xor(p, 1);
      p += __shfl_xor(p, 2);
      p += __shfl_xor(p, 4);
      p += __shfl_xor(p, 8);
      float a = silu_f(p) * cut_s[ee];
      float dv0 = bf2f(dkv_s[ee][128 + vcol]);
      float dv1 = bf2f(dkv_s[ee][128 + vcol + 16]);
      float dv2 = bf2f(dkv_s[ee][128 + vcol + 32]);
      const unsigned short* vr = v_ws + j * 384;
      float v0 = bf2f(vr[vcol]), v1 = bf2f(vr[vcol + 16]), v2 = bf2f(vr[vcol + 32]);
      rx += v0 * dv0 * a;
      float v1m = v1 * dv1, v2m = v2 * dv2;
      const unsigned short* vj = vec_bf + j * 384;
      rv0 += bf2f(vj[ch]) * v1m + v2m * d_s[ee][0];
      rv1 += bf2f(vj[128 + ch]) * v1m + v2m * d_s[ee][1];
      rv2 += bf2f(vj[256 + ch]) * v1m + v2m * d_s[ee][2];
    }
    atomicAdd(&x_agg[cur_i * 128 + ch], rx);
    atomicAdd(&vec_agg[cur_i * 384 + ch], rv0);
    atomicAdd(&vec_agg[cur_i * 384 + 128 + ch], rv1);
    atomicAdd(&vec_agg[cur_i * 384 + 256 + ch], rv2);
  }
}

// ================= Phase C: output projection (f32) + epilogue ===============
__global__ __launch_bounds__(256, 4) void out_kernel(
    const float* __restrict__ x_agg, const float* __restrict__ ow,
    const float* __restrict__ ob, const float* __restrict__ vdot,
    const float* __restrict__ vec3, const float* __restrict__ vec_agg,
    float* __restrict__ dx, float* __restrict__ dvec) {
  __shared__ float xs[16][128];
  const int t = threadIdx.x;
  const int ch = t & 127, g = t >> 7;
  const int node0 = blockIdx.x * 16;

  for (int idx = t; idx < 16 * 128; idx += 256) {
    int n = idx >> 7, c = idx & 127;
    xs[n][c] = x_agg[(size_t)(node0 + n) * 128 + c];
  }
  __syncthreads();

  float a1[8] = {0, 0, 0, 0, 0, 0, 0, 0};
  float a2[8] = {0, 0, 0, 0, 0, 0, 0, 0};
  float a3[8] = {0, 0, 0, 0, 0, 0, 0, 0};
  gemm8x3<128>(ow + ch, ow + 128 + ch, ow + 256 + ch, 384, &xs[0][0], 128,
               g * 8, a1, a2, a3);
  float b1v = ob[ch], b2v = ob[128 + ch], b3v = ob[256 + ch];
#pragma unroll
  for (int n = 0; n < 8; n++) {
    int node = node0 + g * 8 + n;
    float o1 = a1[n] + b1v, o2 = a2[n] + b2v, o3 = a3[n] + b3v;
    dx[(size_t)node * 128 + ch] = vdot[(size_t)node * 128 + ch] * o2 + o3;
#pragma unroll
    for (int c = 0; c < 3; c++) {
      size_t off = (size_t)node * 384 + c * 128 + ch;
      dvec[off] = vec3[off] * o1 + vec_agg[off];
    }
  }
}

extern "C" void kernel_launch(void* const* d_in, const int* in_sizes, int n_in,
                              void* d_out, int out_size, void* d_ws,
                              size_t ws_size, hipStream_t stream) {
  const float* x = (const float*)d_in[0];
  const float* vec = (const float*)d_in[1];
  const float* na = (const float*)d_in[2];
  const int* ei = (const int*)d_in[3];
  const float* r_ij = (const float*)d_in[4];
  const float* f_ij = (const float*)d_in[5];
  const float* d_ijp = (const float*)d_in[6];
  const float* w1 = (const float*)d_in[7];
  const float* b1 = (const float*)d_in[8];
  const float* w2 = (const float*)d_in[9];
  const float* b2 = (const float*)d_in[10];
  const float* lng = (const float*)d_in[11];
  const float* lnb = (const float*)d_in[12];
  const float* qw = (const float*)d_in[13];
  const float* qb = (const float*)d_in[14];
  const float* kw = (const float*)d_in[15];
  const float* kb = (const float*)d_in[16];
  const float* vw = (const float*)d_in[17];
  const float* vb = (const float*)d_in[18];
  const float* ow = (const float*)d_in[19];
  const float* ob = (const float*)d_in[20];
  const float* vecw = (const float*)d_in[21];
  const float* dkw = (const float*)d_in[22];
  const float* dkb = (const float*)d_in[23];
  const float* dvw = (const float*)d_in[24];
  const float* dvb = (const float*)d_in[25];

  float* ws = (float*)d_ws;
  const size_t NH = (size_t)N_NODES * 128;
  const size_t NH3 = (size_t)N_NODES * 384;
  float* vdot_o = ws;              // N*H f32
  float* vec3_o = vdot_o + NH;     // N*3H f32
  float* x_agg = vec3_o + NH3;     // N*H f32
  float* vec_agg = x_agg + NH;     // N*3H f32
  unsigned short* q_bf = (unsigned short*)(vec_agg + NH3);  // N*H
  unsigned short* k_bf = q_bf + NH;                         // N*H
  unsigned short* v_bf = k_bf + NH;                         // N*3H
  unsigned short* vec_bf = v_bf + NH3;                      // N*3H
  unsigned short* wfragE = vec_bf + NH3;                    // 32768
  float* bias512 = (float*)(wfragE + 32768);                // 512 f32
  unsigned short* wfragN = (unsigned short*)(bias512 + 512);
  int* ibuf = (int*)(wfragN + NWF_TOTAL);
  int* counts = ibuf;              // N
  int* cursor = counts + N_NODES;  // N
  int* total = cursor + N_NODES;   // 1
  int* offsets = total + 1;        // N
  int* perm = offsets + N_NODES;   // E

  hipMemsetAsync(x_agg, 0, (NH + NH3) * sizeof(float), stream);
  hipMemsetAsync(counts, 0, (2 * N_NODES + 1) * sizeof(int), stream);

  prep_kernel<<<PREP_D / 256, 256, 0, stream>>>(
      dkw, dkb, dvw, dvb, w1, w2, qw, kw, vw, vecw, vec, wfragE, bias512,
      wfragN, vec_bf);

  node_kernel<<<N_NODES / 16, 256, 0, stream>>>(
      x, vec, na, wfragN, b1, b2, lng, lnb, qb, kb, vb, q_bf, k_bf, v_bf,
      vdot_o, vec3_o);

  hist_kernel<<<(N_EDGES + 255) / 256, 256, 0, stream>>>(ei, counts);
  assign_kernel<<<(N_NODES + 255) / 256, 256, 0, stream>>>(counts, total,
                                                           offsets);
  scatter_kernel<<<(N_EDGES + 255) / 256, 256, 0, stream>>>(ei, offsets, cursor,
                                                            perm);

  edge_kernel<<<N_EDGES / TILE, 256, 0, stream>>>(
      ei, perm, r_ij, f_ij, d_ijp, wfragE, bias512, q_bf, k_bf, v_bf, vec_bf,
      x_agg, vec_agg);

  float* dx = (float*)d_out;
  float* dvec = dx + NH;
  out_kernel<<<N_NODES / 16, 256, 0, stream>>>(x_agg, ow, ob, vdot_o, vec3_o,
                                               vec_agg, dx, dvec);
}